// Round 4
// baseline (167.494 us; speedup 1.0000x reference)
//
#include <hip/hip_runtime.h>

// NearestNeighbor b=8, d=256, n=m=4096.
// Round 4: dual-direction fused GEMM+top2 with double-buffered LDS and
// counted-vmcnt software pipeline (T3min+T4+T5). prep -> nn_pass -> merge -> finalize.

typedef unsigned int uint;
typedef unsigned short ushort_t;
typedef short bf16x8 __attribute__((ext_vector_type(8)));
typedef float f32x4 __attribute__((ext_vector_type(4)));

constexpr int B_ = 8, D_ = 256, N_ = 4096;
constexpr int BM = 128;                        // rows per block
constexpr int BNT = 128;                       // cols per tile iteration
constexpr int BK = 64;                         // k per LDS stage
constexpr int CSPLIT = 4;                      // column split
constexpr int MT_ITERS = (N_ / CSPLIT) / BNT;  // 8
constexpr int KSTEPS = D_ / BK;                // 4
constexpr int NSTAGES = MT_ITERS * KSTEPS;     // 32

// workspace layout (bytes)
constexpr size_t SZ_PANEL = (size_t)B_ * N_ * D_ * 2;   // 16.78 MB each
constexpr size_t OFF_AT = 0;
constexpr size_t OFF_BT = SZ_PANEL;
constexpr size_t OFF_PR = 2 * SZ_PANEL;                 // row partials: 16 slots
constexpr size_t SZ_PR  = (size_t)16 * B_ * N_ * 8;     // 4.2 MB
constexpr size_t OFF_PC = OFF_PR + SZ_PR;               // col partials: 32 slots
constexpr size_t SZ_PC  = (size_t)32 * B_ * N_ * 8;     // 8.4 MB
constexpr size_t OFF_M0 = OFF_PC + SZ_PC;
constexpr size_t OFF_S0 = OFF_M0 + (size_t)B_ * N_ * 4;
constexpr size_t OFF_M1 = OFF_S0 + (size_t)B_ * N_ * 4;

__device__ __forceinline__ ushort_t f2bf(float f) {   // RNE f32->bf16
  uint u = __float_as_uint(f);
  return (ushort_t)((u + 0x7FFFu + ((u >> 16) & 1u)) >> 16);
}

__device__ __forceinline__ void glds16(const void* g, void* l) {
  __builtin_amdgcn_global_load_lds(
      (const __attribute__((address_space(1))) void*)(uintptr_t)(g),
      (__attribute__((address_space(3))) void*)(uint32_t)(uintptr_t)(l),
      16, 0, 0);
}

__device__ __forceinline__ float packkey(float v, uint mask, uint tag) {
  return __uint_as_float((__float_as_uint(v) & mask) | tag);   // v_and_or_b32
}

// top-2 update with invariant s1 >= s2 (v_max + v_med3)
__device__ __forceinline__ void top2(float& s1, float& s2, float k) {
#if __has_builtin(__builtin_amdgcn_fmed3f)
  const float m = __builtin_amdgcn_fmed3f(s1, s2, k);
#else
  const float m = fmaxf(s2, fminf(s1, k));
#endif
  s1 = fmaxf(s1, k);
  s2 = m;
}

// merge two sorted top-2 pairs
__device__ __forceinline__ void top2merge(float& s1, float& s2, float o1, float o2) {
  const float lo = fminf(s1, o1);
  s1 = fmaxf(s1, o1);
  s2 = fmaxf(lo, fmaxf(s2, o2));
}

// ---- transpose + convert: [b][256][4096] f32 -> [b][4096][256] bf16 ----
__global__ __launch_bounds__(256)
void prep_kernel(const float* __restrict__ in0, const float* __restrict__ in1,
                 ushort_t* __restrict__ At, ushort_t* __restrict__ Bt)
{
  __shared__ ushort_t tile[32][33];
  const int z = blockIdx.z;
  const float* src = (z < 8) ? in0 : in1;
  ushort_t* dst = (z < 8) ? At : Bt;
  const int b = z & 7;
  const int k0 = blockIdx.y * 32, n0 = blockIdx.x * 32;
  const int t = threadIdx.x;
  const int kl = t >> 3, n4 = (t & 7) * 4;
  const float4 v = *(const float4*)(src + ((size_t)b * D_ + k0 + kl) * N_ + n0 + n4);
  tile[kl][n4 + 0] = f2bf(v.x); tile[kl][n4 + 1] = f2bf(v.y);
  tile[kl][n4 + 2] = f2bf(v.z); tile[kl][n4 + 3] = f2bf(v.w);
  __syncthreads();
  const int nl = t >> 3, k4 = (t & 7) * 4;
  ushort4 o;
  o.x = tile[k4 + 0][nl]; o.y = tile[k4 + 1][nl];
  o.z = tile[k4 + 2][nl]; o.w = tile[k4 + 3][nl];
  *(ushort4*)(dst + ((size_t)b * N_ + n0 + nl) * D_ + k0 + k4) = o;
}

// ---- single fused GEMM + dual-direction top-2, pipelined ----
__global__ __launch_bounds__(256, 2)
void nn_pass(const ushort_t* __restrict__ A, const ushort_t* __restrict__ Bp,
             uint2* __restrict__ partR, uint2* __restrict__ partC)
{
  __shared__ ushort_t As[2][BM * BK];   // 2 x 16 KB
  __shared__ ushort_t Bs[2][BNT * BK];  // 2 x 16 KB

  const int t = threadIdx.x;
  const int bid = blockIdx.x;
  const int b = bid & 7;                   // XCD-pinned batch
  const int rb = (bid >> 3) & 31;
  const int cs = bid >> 8;
  const size_t bOff = (size_t)b * N_ * D_;
  const int r0 = rb * BM;
  const int c0 = cs * (N_ / CSPLIT);

  const int l = t & 63, wn = t >> 6;       // 4 waves: full rows, 32-col slice
  const int l15 = l & 15, g = l >> 4;
  const uint swz = (uint)(l & 7) << 4;     // read-side XOR (bytes)

  // staging: 4 chunks of 16B per operand per thread per K-step (pre-swizzled src)
  const ushort_t* srcA[4]; const ushort_t* srcB[4]; int ldsq[4];
  #pragma unroll
  for (int i = 0; i < 4; ++i) {
    const int q = i * 256 + t;
    const int r = q >> 3;
    const int kfl = (((q & 7) ^ (r & 7)) << 3);
    srcA[i] = A  + bOff + (size_t)(r0 + r) * D_ + kfl;
    srcB[i] = Bp + bOff + (size_t)(c0 + r) * D_ + kfl;
    ldsq[i] = q * 16;
  }

  // stage sn: A k-slice (sn&3), B tile (sn>>2), into buffer (sn&1)
  auto STAGE = [&](int sn) {
    const size_t aoff = (size_t)(sn & 3) * BK;
    const size_t boff = (size_t)(sn >> 2) * BNT * D_ + (size_t)(sn & 3) * BK;
    char* dA = (char*)As[sn & 1];
    char* dB = (char*)Bs[sn & 1];
    #pragma unroll
    for (int i = 0; i < 4; ++i) {
      glds16(srcA[i] + aoff, dA + ldsq[i]);
      glds16(srcB[i] + boff, dB + ldsq[i]);
    }
  };

  const float NEG = __uint_as_float(0xFF800000u);  // -inf
  float rs1[8][4], rs2[8][4];
  #pragma unroll
  for (int mi = 0; mi < 8; ++mi)
    #pragma unroll
    for (int rg = 0; rg < 4; ++rg) { rs1[mi][rg] = NEG; rs2[mi][rg] = NEG; }

  STAGE(0);

  for (int mt = 0; mt < MT_ITERS; ++mt) {
    f32x4 acc[8][2];
    #pragma unroll
    for (int mi = 0; mi < 8; ++mi)
      #pragma unroll
      for (int ni = 0; ni < 2; ++ni) acc[mi][ni] = (f32x4){0.f, 0.f, 0.f, 0.f};

    #pragma unroll
    for (int ks = 0; ks < KSTEPS; ++ks) {
      const int s = mt * KSTEPS + ks;
      // issue next stage, then wait ONLY for stage s (8 loads stay in flight)
      if (s + 1 < NSTAGES) {
        STAGE(s + 1);
        asm volatile("s_waitcnt vmcnt(8)" ::: "memory");
      } else {
        asm volatile("s_waitcnt vmcnt(0)" ::: "memory");
      }
      __builtin_amdgcn_s_barrier();

      const char* cA = (const char*)As[ks & 1];
      const char* cB = (const char*)Bs[ks & 1];
      #pragma unroll
      for (int kk = 0; kk < 2; ++kk) {
        const uint kb = (uint)(kk * 64 + g * 16) ^ swz;
        bf16x8 a[8], bb[2];
        #pragma unroll
        for (int mi = 0; mi < 8; ++mi)
          a[mi] = *(const bf16x8*)(cA + (mi * 16 + l15) * (BK * 2) + kb);
        #pragma unroll
        for (int ni = 0; ni < 2; ++ni)
          bb[ni] = *(const bf16x8*)(cB + (wn * 32 + ni * 16 + l15) * (BK * 2) + kb);
        __builtin_amdgcn_s_setprio(1);
        #pragma unroll
        for (int mi = 0; mi < 8; ++mi)
          #pragma unroll
          for (int ni = 0; ni < 2; ++ni)
            acc[mi][ni] = __builtin_amdgcn_mfma_f32_16x16x32_bf16(a[mi], bb[ni], acc[mi][ni], 0, 0, 0);
        __builtin_amdgcn_s_setprio(0);
      }
      __builtin_amdgcn_s_barrier();   // all reads of buf[ks&1] done before restage
    }

    // ---- row-direction fold (state persists across mt) ----
    const int colbase = mt * BNT + wn * 32;
    const uint tagc0 = (uint)(1023 - (colbase + l15));
    const uint tagc1 = (uint)(1023 - (colbase + 16 + l15));
    #pragma unroll
    for (int mi = 0; mi < 8; ++mi)
      #pragma unroll
      for (int rg = 0; rg < 4; ++rg) {
        top2(rs1[mi][rg], rs2[mi][rg], packkey(acc[mi][0][rg], 0xFFFFFC00u, tagc0));
        top2(rs1[mi][rg], rs2[mi][rg], packkey(acc[mi][1][rg], 0xFFFFFC00u, tagc1));
      }

    // ---- col-direction fold (per-tile, merged across g-groups) ----
    const uint tgb = (uint)(127 - g * 4);
    #pragma unroll
    for (int ni = 0; ni < 2; ++ni) {
      float c1 = NEG, c2 = NEG;
      #pragma unroll
      for (int mi = 0; mi < 8; ++mi)
        #pragma unroll
        for (int rg = 0; rg < 4; ++rg)
          top2(c1, c2, packkey(acc[mi][ni][rg], 0xFFFFFF00u, tgb - (uint)(mi * 16 + rg)));
      #pragma unroll
      for (int off = 16; off <= 32; off <<= 1) {
        const float o1 = __shfl_xor(c1, off);
        const float o2 = __shfl_xor(c2, off);
        top2merge(c1, c2, o1, o2);
      }
      if (g == 0)
        partC[((size_t)rb * B_ + b) * N_ + c0 + colbase + ni * 16 + l15] =
            make_uint2(__float_as_uint(c1), __float_as_uint(c2));
    }
  }

  // ---- row merge across 16 column-lanes, write per-(cs,wn) partials ----
  #pragma unroll
  for (int off = 1; off < 16; off <<= 1) {
    #pragma unroll
    for (int mi = 0; mi < 8; ++mi)
      #pragma unroll
      for (int rg = 0; rg < 4; ++rg) {
        const float o1 = __shfl_xor(rs1[mi][rg], off);
        const float o2 = __shfl_xor(rs2[mi][rg], off);
        top2merge(rs1[mi][rg], rs2[mi][rg], o1, o2);
      }
  }
  if (l15 == 0) {
    #pragma unroll
    for (int mi = 0; mi < 8; ++mi)
      #pragma unroll
      for (int rg = 0; rg < 4; ++rg)
        partR[((size_t)(cs * 4 + wn) * B_ + b) * N_ + r0 + mi * 16 + g * 4 + rg] =
            make_uint2(__float_as_uint(rs1[mi][rg]), __float_as_uint(rs2[mi][rg]));
  }
}

// ---- fold partials, decode, ratio test ----
__global__ __launch_bounds__(256)
void merge_kernel(const uint2* __restrict__ pR, const uint2* __restrict__ pC,
                  int* __restrict__ m0, float* __restrict__ s0, int* __restrict__ m1)
{
  const int tid = blockIdx.x * 256 + threadIdx.x;
  if (tid >= 2 * B_ * N_) return;
  const int dir = tid >> 15;
  const int i = tid & (B_ * N_ - 1);
  const float NEG = __uint_as_float(0xFF800000u);

  if (dir == 0) {
    float s1 = NEG, s2 = NEG; int bs = 0;
    #pragma unroll
    for (int sl = 0; sl < 16; ++sl) {
      const uint2 v = pR[(size_t)sl * B_ * N_ + i];
      const float o1 = __uint_as_float(v.x), o2 = __uint_as_float(v.y);
      bs = (o1 > s1) ? sl : bs;
      top2merge(s1, s2, o1, o2);
    }
    const uint k1 = __float_as_uint(s1);
    const int col = (bs >> 2) * 1024 + 1023 - (int)(k1 & 0x3FFu);
    const float v1 = __uint_as_float(k1 & 0xFFFFFC00u);
    const float v2 = __uint_as_float(__float_as_uint(s2) & 0xFFFFFC00u);
    const bool ok = (1.0f - v1) <= 0.64f * (1.0f - v2);
    m0[i] = ok ? col : -1;
    s0[i] = ok ? (v1 + 1.0f) * 0.5f : 0.0f;
  } else {
    float s1 = NEG, s2 = NEG; int bs = 0;
    #pragma unroll 8
    for (int sl = 0; sl < 32; ++sl) {
      const uint2 v = pC[(size_t)sl * B_ * N_ + i];
      const float o1 = __uint_as_float(v.x), o2 = __uint_as_float(v.y);
      bs = (o1 > s1) ? sl : bs;
      top2merge(s1, s2, o1, o2);
    }
    const uint k1 = __float_as_uint(s1);
    const int row = bs * 128 + 127 - (int)(k1 & 0x7Fu);
    const float v1 = __uint_as_float(k1 & 0xFFFFFF00u);
    const float v2 = __uint_as_float(__float_as_uint(s2) & 0xFFFFFF00u);
    const bool ok = (1.0f - v1) <= 0.64f * (1.0f - v2);
    m1[i] = ok ? row : -1;
  }
}

// ---- mutual check + output ----
__global__ __launch_bounds__(256)
void finalize_kernel(const int* __restrict__ m0, const float* __restrict__ s0,
                     const int* __restrict__ m1, float* __restrict__ out)
{
  const int idx = blockIdx.x * 256 + threadIdx.x;
  if (idx >= B_ * N_) return;
  const int b = idx >> 12;
  const int n = idx & (N_ - 1);
  const int mm = m0[idx];
  int res = -1;
  if (mm > -1 && m1[((size_t)b << 12) + mm] == n) res = mm;
  out[idx] = (float)res;
  out[B_ * N_ + idx] = s0[idx];
}

extern "C" void kernel_launch(void* const* d_in, const int* in_sizes, int n_in,
                              void* d_out, int out_size, void* d_ws, size_t ws_size,
                              hipStream_t stream)
{
  const float* d0 = (const float*)d_in[0];
  const float* d1 = (const float*)d_in[1];
  float* out = (float*)d_out;

  ushort_t* At = (ushort_t*)((char*)d_ws + OFF_AT);
  ushort_t* Bt = (ushort_t*)((char*)d_ws + OFF_BT);
  uint2* PR = (uint2*)((char*)d_ws + OFF_PR);
  uint2* PC = (uint2*)((char*)d_ws + OFF_PC);
  int*   m0 = (int*)  ((char*)d_ws + OFF_M0);
  float* s0 = (float*)((char*)d_ws + OFF_S0);
  int*   m1 = (int*)  ((char*)d_ws + OFF_M1);

  prep_kernel<<<dim3(N_ / 32, D_ / 32, 16), 256, 0, stream>>>(d0, d1, At, Bt);
  nn_pass<<<dim3(B_ * (N_ / BM) * CSPLIT), 256, 0, stream>>>(At, Bt, PR, PC);
  merge_kernel<<<dim3(2 * B_ * N_ / 256), 256, 0, stream>>>(PR, PC, m0, s0, m1);
  finalize_kernel<<<dim3(B_ * N_ / 256), 256, 0, stream>>>(m0, s0, m1, out);
}

// Round 5
// 150.652 us; speedup vs baseline: 1.1118x; 1.1118x over previous
//
#include <hip/hip_runtime.h>

// NearestNeighbor b=8, d=256, n=m=4096.
// Round 5: lockstep single-buffer GEMM+dual-top2, occupancy-optimized:
// 4 waves x (64 rows x 32 cols), acc 32 regs, rs 32 regs, 24KB LDS, 4 blocks/CU.

typedef unsigned int uint;
typedef unsigned short ushort_t;
typedef short bf16x8 __attribute__((ext_vector_type(8)));
typedef float f32x4 __attribute__((ext_vector_type(4)));

constexpr int B_ = 8, D_ = 256, N_ = 4096;
constexpr int BMR = 64;                        // rows per block
constexpr int BNT = 128;                       // cols per tile iteration
constexpr int BK = 64;                         // k per LDS stage
constexpr int CSPLIT = 4;                      // column split
constexpr int MT_ITERS = (N_ / CSPLIT) / BNT;  // 8
constexpr int KSTEPS = D_ / BK;                // 4

// workspace layout (bytes)
constexpr size_t SZ_PANEL = (size_t)B_ * N_ * D_ * 2;   // 16.78 MB each
constexpr size_t OFF_AT = 0;
constexpr size_t OFF_BT = SZ_PANEL;
constexpr size_t OFF_PR = 2 * SZ_PANEL;                 // row partials: 16 slots
constexpr size_t SZ_PR  = (size_t)16 * B_ * N_ * 8;     // 4.2 MB
constexpr size_t OFF_PC = OFF_PR + SZ_PR;               // col partials: 64 slots
constexpr size_t SZ_PC  = (size_t)64 * B_ * N_ * 8;     // 16.8 MB
constexpr size_t OFF_M0 = OFF_PC + SZ_PC;
constexpr size_t OFF_S0 = OFF_M0 + (size_t)B_ * N_ * 4;
constexpr size_t OFF_M1 = OFF_S0 + (size_t)B_ * N_ * 4;

__device__ __forceinline__ ushort_t f2bf(float f) {   // RNE f32->bf16
  uint u = __float_as_uint(f);
  return (ushort_t)((u + 0x7FFFu + ((u >> 16) & 1u)) >> 16);
}

__device__ __forceinline__ void glds16(const void* g, void* l) {
  __builtin_amdgcn_global_load_lds(
      (const __attribute__((address_space(1))) void*)(uintptr_t)(g),
      (__attribute__((address_space(3))) void*)(uint32_t)(uintptr_t)(l),
      16, 0, 0);
}

__device__ __forceinline__ float packkey(float v, uint mask, uint tag) {
  return __uint_as_float((__float_as_uint(v) & mask) | tag);   // v_and_or_b32
}

// top-2 update with invariant s1 >= s2 (v_max + v_med3)
__device__ __forceinline__ void top2(float& s1, float& s2, float k) {
#if __has_builtin(__builtin_amdgcn_fmed3f)
  const float m = __builtin_amdgcn_fmed3f(s1, s2, k);
#else
  const float m = fmaxf(s2, fminf(s1, k));
#endif
  s1 = fmaxf(s1, k);
  s2 = m;
}

// merge two sorted top-2 pairs
__device__ __forceinline__ void top2merge(float& s1, float& s2, float o1, float o2) {
  const float lo = fminf(s1, o1);
  s1 = fmaxf(s1, o1);
  s2 = fmaxf(lo, fmaxf(s2, o2));
}

// ---- transpose + convert: [b][256][4096] f32 -> [b][4096][256] bf16 ----
__global__ __launch_bounds__(256)
void prep_kernel(const float* __restrict__ in0, const float* __restrict__ in1,
                 ushort_t* __restrict__ At, ushort_t* __restrict__ Bt)
{
  __shared__ ushort_t tile[32][33];
  const int z = blockIdx.z;
  const float* src = (z < 8) ? in0 : in1;
  ushort_t* dst = (z < 8) ? At : Bt;
  const int b = z & 7;
  const int k0 = blockIdx.y * 32, n0 = blockIdx.x * 32;
  const int t = threadIdx.x;
  const int kl = t >> 3, n4 = (t & 7) * 4;
  const float4 v = *(const float4*)(src + ((size_t)b * D_ + k0 + kl) * N_ + n0 + n4);
  tile[kl][n4 + 0] = f2bf(v.x); tile[kl][n4 + 1] = f2bf(v.y);
  tile[kl][n4 + 2] = f2bf(v.z); tile[kl][n4 + 3] = f2bf(v.w);
  __syncthreads();
  const int nl = t >> 3, k4 = (t & 7) * 4;
  ushort4 o;
  o.x = tile[k4 + 0][nl]; o.y = tile[k4 + 1][nl];
  o.z = tile[k4 + 2][nl]; o.w = tile[k4 + 3][nl];
  *(ushort4*)(dst + ((size_t)b * N_ + n0 + nl) * D_ + k0 + k4) = o;
}

// ---- fused GEMM + dual-direction top-2, lockstep, high-occupancy ----
// Block: 64 rows x 1024-col scan. 4 waves, wave wn = 64 rows x 32 cols.
// Row keys: 22 bits | 10-bit inv col tag. Col keys: 26 bits | 6-bit inv row tag.
__global__ __launch_bounds__(256, 4)
void nn_pass(const ushort_t* __restrict__ A, const ushort_t* __restrict__ Bp,
             uint2* __restrict__ partR, uint2* __restrict__ partC)
{
  __shared__ ushort_t As[BMR * BK];   // 8 KB
  __shared__ ushort_t Bs[BNT * BK];   // 16 KB

  const int t = threadIdx.x;
  const int bid = blockIdx.x;
  const int b = bid & 7;                   // XCD-pinned batch
  const int rb = (bid >> 3) & 63;
  const int cs = bid >> 9;
  const size_t bOff = (size_t)b * N_ * D_;
  const int r0 = rb * BMR;
  const int c0 = cs * (N_ / CSPLIT);

  const int l = t & 63, wn = t >> 6;       // wave wn: all 64 rows, 32-col slice
  const int l15 = l & 15, g = l >> 4;

  // staging offsets (shared form for A and B): thread covers chunk q = i*256+t
  // row r = q>>3, swizzled chunk col = (q&7)^(r&7); i-steps add 32 rows.
  const int off0 = (t >> 3) * D_ + (((t & 7) ^ ((t >> 3) & 7)) << 3);  // elements
  const int lds0 = t * 16;                                             // bytes
  const ushort_t* Abase = A  + bOff + (size_t)r0 * D_;
  const ushort_t* Bbase = Bp + bOff + (size_t)c0 * D_;

  // LDS read addressing
  const int rowb = l15 * 128;                 // byte offset of row l15 (128B rows)
  const uint kb0 = (uint)(g * 16) ^ ((uint)(l & 7) << 4);

  const float NEG = __uint_as_float(0xFF800000u);  // -inf
  float rs1[4][4], rs2[4][4];
  #pragma unroll
  for (int mi = 0; mi < 4; ++mi)
    #pragma unroll
    for (int rg = 0; rg < 4; ++rg) { rs1[mi][rg] = NEG; rs2[mi][rg] = NEG; }

  for (int mt = 0; mt < MT_ITERS; ++mt) {
    f32x4 acc[4][2];
    #pragma unroll
    for (int mi = 0; mi < 4; ++mi)
      #pragma unroll
      for (int ni = 0; ni < 2; ++ni) acc[mi][ni] = (f32x4){0.f, 0.f, 0.f, 0.f};

    #pragma unroll
    for (int ks = 0; ks < KSTEPS; ++ks) {
      const int aoff = ks * BK;
      const int boff = mt * BNT * D_ + ks * BK;
      __syncthreads();                       // prev stage readers done
      #pragma unroll
      for (int i = 0; i < 2; ++i)
        glds16(Abase + off0 + i * 32 * D_ + aoff, (char*)As + lds0 + i * 4096);
      #pragma unroll
      for (int i = 0; i < 4; ++i)
        glds16(Bbase + off0 + i * 32 * D_ + boff, (char*)Bs + lds0 + i * 4096);
      __syncthreads();                       // drains vmcnt(0) (lockstep spring)

      #pragma unroll
      for (int kk = 0; kk < 2; ++kk) {
        const uint kb = kb0 ^ (uint)(kk * 64);
        bf16x8 a[4];
        #pragma unroll
        for (int mi = 0; mi < 4; ++mi)
          a[mi] = *(const bf16x8*)((const char*)As + mi * 2048 + rowb + kb);
        __builtin_amdgcn_s_setprio(1);
        #pragma unroll
        for (int ni = 0; ni < 2; ++ni) {
          const bf16x8 bb = *(const bf16x8*)((const char*)Bs + wn * 4096 + ni * 2048 + rowb + kb);
          #pragma unroll
          for (int mi = 0; mi < 4; ++mi)
            acc[mi][ni] = __builtin_amdgcn_mfma_f32_16x16x32_bf16(a[mi], bb, acc[mi][ni], 0, 0, 0);
        }
        __builtin_amdgcn_s_setprio(0);
      }
    }

    // ---- row-direction fold (state persists across mt) ----
    const int colbase = mt * BNT + wn * 32;
    const uint tagc0 = (uint)(1023 - (colbase + l15));
    const uint tagc1 = tagc0 - 16;
    #pragma unroll
    for (int mi = 0; mi < 4; ++mi)
      #pragma unroll
      for (int rg = 0; rg < 4; ++rg) {
        top2(rs1[mi][rg], rs2[mi][rg], packkey(acc[mi][0][rg], 0xFFFFFC00u, tagc0));
        top2(rs1[mi][rg], rs2[mi][rg], packkey(acc[mi][1][rg], 0xFFFFFC00u, tagc1));
      }

    // ---- col-direction fold (per-tile; 6-bit inv row tag over 64 rows) ----
    const uint tgb = (uint)(63 - g * 4);
    #pragma unroll
    for (int ni = 0; ni < 2; ++ni) {
      float c1 = NEG, c2 = NEG;
      #pragma unroll
      for (int mi = 0; mi < 4; ++mi)
        #pragma unroll
        for (int rg = 0; rg < 4; ++rg)
          top2(c1, c2, packkey(acc[mi][ni][rg], 0xFFFFFFC0u, tgb - (uint)(mi * 16 + rg)));
      #pragma unroll
      for (int off = 16; off <= 32; off <<= 1) {
        const float o1 = __shfl_xor(c1, off);
        const float o2 = __shfl_xor(c2, off);
        top2merge(c1, c2, o1, o2);
      }
      if (g == 0)
        partC[((size_t)rb * B_ + b) * N_ + c0 + colbase + ni * 16 + l15] =
            make_uint2(__float_as_uint(c1), __float_as_uint(c2));
    }
  }

  // ---- row merge across 16 column-lanes, write per-(cs,wn) partials ----
  #pragma unroll
  for (int off = 1; off < 16; off <<= 1) {
    #pragma unroll
    for (int mi = 0; mi < 4; ++mi)
      #pragma unroll
      for (int rg = 0; rg < 4; ++rg) {
        const float o1 = __shfl_xor(rs1[mi][rg], off);
        const float o2 = __shfl_xor(rs2[mi][rg], off);
        top2merge(rs1[mi][rg], rs2[mi][rg], o1, o2);
      }
  }
  if (l15 == 0) {
    #pragma unroll
    for (int mi = 0; mi < 4; ++mi)
      #pragma unroll
      for (int rg = 0; rg < 4; ++rg)
        partR[((size_t)(cs * 4 + wn) * B_ + b) * N_ + r0 + mi * 16 + g * 4 + rg] =
            make_uint2(__float_as_uint(rs1[mi][rg]), __float_as_uint(rs2[mi][rg]));
  }
}

// ---- fold partials, decode, ratio test ----
__global__ __launch_bounds__(256)
void merge_kernel(const uint2* __restrict__ pR, const uint2* __restrict__ pC,
                  int* __restrict__ m0, float* __restrict__ s0, int* __restrict__ m1)
{
  const int tid = blockIdx.x * 256 + threadIdx.x;
  if (tid >= 2 * B_ * N_) return;
  const int dir = tid >> 15;
  const int i = tid & (B_ * N_ - 1);
  const float NEG = __uint_as_float(0xFF800000u);

  if (dir == 0) {
    float s1 = NEG, s2 = NEG; int bs = 0;
    #pragma unroll
    for (int sl = 0; sl < 16; ++sl) {
      const uint2 v = pR[(size_t)sl * B_ * N_ + i];
      const float o1 = __uint_as_float(v.x), o2 = __uint_as_float(v.y);
      bs = (o1 > s1) ? sl : bs;
      top2merge(s1, s2, o1, o2);
    }
    const uint k1 = __float_as_uint(s1);
    const int col = (bs >> 2) * 1024 + 1023 - (int)(k1 & 0x3FFu);
    const float v1 = __uint_as_float(k1 & 0xFFFFFC00u);
    const float v2 = __uint_as_float(__float_as_uint(s2) & 0xFFFFFC00u);
    const bool ok = (1.0f - v1) <= 0.64f * (1.0f - v2);
    m0[i] = ok ? col : -1;
    s0[i] = ok ? (v1 + 1.0f) * 0.5f : 0.0f;
  } else {
    float s1 = NEG, s2 = NEG; int bs = 0;
    #pragma unroll 8
    for (int sl = 0; sl < 64; ++sl) {
      const uint2 v = pC[(size_t)sl * B_ * N_ + i];
      const float o1 = __uint_as_float(v.x), o2 = __uint_as_float(v.y);
      bs = (o1 > s1) ? sl : bs;
      top2merge(s1, s2, o1, o2);
    }
    const uint k1 = __float_as_uint(s1);
    const int row = bs * 64 + 63 - (int)(k1 & 0x3Fu);
    const float v1 = __uint_as_float(k1 & 0xFFFFFFC0u);
    const float v2 = __uint_as_float(__float_as_uint(s2) & 0xFFFFFFC0u);
    const bool ok = (1.0f - v1) <= 0.64f * (1.0f - v2);
    m1[i] = ok ? row : -1;
  }
}

// ---- mutual check + output ----
__global__ __launch_bounds__(256)
void finalize_kernel(const int* __restrict__ m0, const float* __restrict__ s0,
                     const int* __restrict__ m1, float* __restrict__ out)
{
  const int idx = blockIdx.x * 256 + threadIdx.x;
  if (idx >= B_ * N_) return;
  const int b = idx >> 12;
  const int n = idx & (N_ - 1);
  const int mm = m0[idx];
  int res = -1;
  if (mm > -1 && m1[((size_t)b << 12) + mm] == n) res = mm;
  out[idx] = (float)res;
  out[B_ * N_ + idx] = s0[idx];
}

extern "C" void kernel_launch(void* const* d_in, const int* in_sizes, int n_in,
                              void* d_out, int out_size, void* d_ws, size_t ws_size,
                              hipStream_t stream)
{
  const float* d0 = (const float*)d_in[0];
  const float* d1 = (const float*)d_in[1];
  float* out = (float*)d_out;

  ushort_t* At = (ushort_t*)((char*)d_ws + OFF_AT);
  ushort_t* Bt = (ushort_t*)((char*)d_ws + OFF_BT);
  uint2* PR = (uint2*)((char*)d_ws + OFF_PR);
  uint2* PC = (uint2*)((char*)d_ws + OFF_PC);
  int*   m0 = (int*)  ((char*)d_ws + OFF_M0);
  float* s0 = (float*)((char*)d_ws + OFF_S0);
  int*   m1 = (int*)  ((char*)d_ws + OFF_M1);

  prep_kernel<<<dim3(N_ / 32, D_ / 32, 16), 256, 0, stream>>>(d0, d1, At, Bt);
  nn_pass<<<dim3(B_ * (N_ / BMR) * CSPLIT), 256, 0, stream>>>(At, Bt, PR, PC);
  merge_kernel<<<dim3(2 * B_ * N_ / 256), 256, 0, stream>>>(PR, PC, m0, s0, m1);
  finalize_kernel<<<dim3(B_ * N_ / 256), 256, 0, stream>>>(m0, s0, m1, out);
}

// Round 6
// 100.482 us; speedup vs baseline: 1.6669x; 1.4993x over previous
//
#include <hip/hip_runtime.h>

// NearestNeighbor b=8, d=256, n=m=4096.
// Round 6: MX-fp8 (e4m3, unit scales) K=128 MFMA; A-tile LDS-resident with
// register-hoisted A-frags; lockstep B staging. prep -> nn_pass -> merge -> finalize.

typedef unsigned int uint;
typedef unsigned char uchar;
typedef int i32x4 __attribute__((ext_vector_type(4)));
typedef int i32x8 __attribute__((ext_vector_type(8)));
typedef float f32x4 __attribute__((ext_vector_type(4)));

constexpr int B_ = 8, D_ = 256, N_ = 4096;
constexpr int BMR = 128;                       // rows per block
constexpr int BNT = 128;                       // cols per tile iteration
constexpr int CSPLIT = 4;                      // column split
constexpr int MT_ITERS = (N_ / CSPLIT) / BNT;  // 8
constexpr int NSTAGES = MT_ITERS * 2;          // 16 B-stages (K = 2 x 128)

// workspace layout (bytes)
constexpr size_t SZ_PANEL = (size_t)B_ * N_ * D_;        // 8.39 MB (fp8)
constexpr size_t OFF_AT = 0;
constexpr size_t OFF_BT = SZ_PANEL;
constexpr size_t OFF_PR = 2 * SZ_PANEL;                  // row partials: 8 slots
constexpr size_t SZ_PR  = (size_t)8 * B_ * N_ * 8;       // 2.1 MB
constexpr size_t OFF_PC = OFF_PR + SZ_PR;                // col partials: 64 slots
constexpr size_t SZ_PC  = (size_t)64 * B_ * N_ * 8;      // 16.8 MB
constexpr size_t OFF_M0 = OFF_PC + SZ_PC;
constexpr size_t OFF_S0 = OFF_M0 + (size_t)B_ * N_ * 4;
constexpr size_t OFF_M1 = OFF_S0 + (size_t)B_ * N_ * 4;

// f32 -> OCP e4m3fn (RNE, saturating). Inputs here are in [-1,1].
__device__ __forceinline__ uchar f2e4m3(float f) {
  uint u = __float_as_uint(f);
  uint s = (u >> 24) & 0x80u;
  uint mag = u & 0x7FFFFFFFu;
  if (mag >= 0x43E00000u) return (uchar)(s | 0x7Eu);       // clamp to ±448
  int e = (int)(mag >> 23) - 127;
  if (e >= -6) {                                            // normal range
    uint m = (mag >> 20) & 7u;
    uint rem = mag & 0xFFFFFu;
    m += (rem > 0x80000u) || (rem == 0x80000u && (m & 1u));
    uint ef = (uint)(e + 7);
    if (m == 8u) { m = 0u; ef += 1u; }
    if (ef >= 16u) return (uchar)(s | 0x7Eu);
    return (uchar)(s | (ef << 3) | m);
  } else {                                                  // subnormal: RNE(|f|*512)
    int q = __float2int_rn(__uint_as_float(mag) * 512.0f);
    if (q >= 8) return (uchar)(s | 0x08u);
    return (uchar)(s | (uint)q);
  }
}

__device__ __forceinline__ void glds16(const void* g, void* l) {
  __builtin_amdgcn_global_load_lds(
      (const __attribute__((address_space(1))) void*)(uintptr_t)(g),
      (__attribute__((address_space(3))) void*)(uint32_t)(uintptr_t)(l),
      16, 0, 0);
}

__device__ __forceinline__ float packkey(float v, uint mask, uint tag) {
  return __uint_as_float((__float_as_uint(v) & mask) | tag);   // v_and_or_b32
}

__device__ __forceinline__ void top2(float& s1, float& s2, float k) {
#if __has_builtin(__builtin_amdgcn_fmed3f)
  const float m = __builtin_amdgcn_fmed3f(s1, s2, k);
#else
  const float m = fmaxf(s2, fminf(s1, k));
#endif
  s1 = fmaxf(s1, k);
  s2 = m;
}

__device__ __forceinline__ void top2merge(float& s1, float& s2, float o1, float o2) {
  const float lo = fminf(s1, o1);
  s1 = fmaxf(s1, o1);
  s2 = fmaxf(lo, fmaxf(s2, o2));
}

// ---- transpose + convert: [b][256][4096] f32 -> [b][4096][256] e4m3 ----
__global__ __launch_bounds__(256)
void prep_kernel(const float* __restrict__ in0, const float* __restrict__ in1,
                 uchar* __restrict__ At, uchar* __restrict__ Bt)
{
  __shared__ uchar tile[32][36];
  const int z = blockIdx.z;
  const float* src = (z < 8) ? in0 : in1;
  uchar* dst = (z < 8) ? At : Bt;
  const int b = z & 7;
  const int k0 = blockIdx.y * 32, n0 = blockIdx.x * 32;
  const int t = threadIdx.x;
  const int kl = t >> 3, n4 = (t & 7) * 4;
  const float4 v = *(const float4*)(src + ((size_t)b * D_ + k0 + kl) * N_ + n0 + n4);
  tile[kl][n4 + 0] = f2e4m3(v.x); tile[kl][n4 + 1] = f2e4m3(v.y);
  tile[kl][n4 + 2] = f2e4m3(v.z); tile[kl][n4 + 3] = f2e4m3(v.w);
  __syncthreads();
  const int nl = t >> 3, k4 = (t & 7) * 4;
  uchar4 o;
  o.x = tile[k4 + 0][nl]; o.y = tile[k4 + 1][nl];
  o.z = tile[k4 + 2][nl]; o.w = tile[k4 + 3][nl];
  *(uchar4*)(dst + ((size_t)b * N_ + n0 + nl) * D_ + k0 + k4) = o;
}

// ---- fused GEMM (MX-fp8 K=128) + dual-direction top-2 ----
// Block: 128 rows x 1024-col scan. 4 waves 2Mx2N: wave (wm,wn) = 64x64 of tile.
// A tile resident in LDS full-K (32KB), A-frags hoisted to regs (a[2][4]).
// Row keys: 22 bits | 10-bit inv col tag. Col keys: 26 bits | 6-bit inv row tag.
__global__ __launch_bounds__(256, 2)
void nn_pass(const uchar* __restrict__ A, const uchar* __restrict__ Bp,
             uint2* __restrict__ partR, uint2* __restrict__ partC)
{
  __shared__ uchar As[BMR * 256];   // 32 KB, full K
  __shared__ uchar Bs[BNT * 128];   // 16 KB, per-stage

  const int t = threadIdx.x;
  const int bid = blockIdx.x;
  const int b = bid & 7;                   // XCD-pinned batch
  const int rb = (bid >> 3) & 31;
  const int cs = bid >> 8;
  const size_t bOff = (size_t)b * N_ * D_;
  const int r0 = rb * BMR;
  const int c0 = cs * (N_ / CSPLIT);

  const int l = t & 63, wid = t >> 6, wm = wid >> 1, wn = wid & 1;
  const int l15 = l & 15, g = l >> 4;

  // staging addressing (pre-swizzled global source, linear LDS dest)
  // A: 16-granule rows (256B): chunk q=i*256+t -> r=i*16+(t>>4), c=t&15
  const int offA = (t >> 4) * D_ + ((((t & 15) ^ (t >> 4)) & 15) << 4);
  // B: 8-granule rows (128B): chunk q=i*256+t -> r=i*32+(t>>3), c=t&7
  const int offB = (t >> 3) * D_ + ((((t & 7) ^ ((t >> 3) & 7))) << 4);
  const int lds0 = t * 16;

  const uchar* Ab = A  + bOff + (size_t)r0 * D_;
  const uchar* Bb = Bp + bOff + (size_t)c0 * D_;

  // ---- prologue: stage full-K A tile + B stage 0, one drain ----
  #pragma unroll
  for (int i = 0; i < 8; ++i)
    glds16(Ab + offA + i * 4096, (char*)As + lds0 + i * 4096);
  #pragma unroll
  for (int i = 0; i < 4; ++i)
    glds16(Bb + offB + i * 8192, (char*)Bs + lds0 + i * 4096);
  __syncthreads();   // vmcnt(0) drain: A + B0 ready

  // ---- hoist A fragments: a[ks][mi], 32B/lane each ----
  i32x8 afr[2][4];
  #pragma unroll
  for (int ks = 0; ks < 2; ++ks)
    #pragma unroll
    for (int mi = 0; mi < 4; ++mi) {
      const int row = wm * 64 + mi * 16 + l15;    // row & 15 == l15
      const uchar* base = As + row * 256;
      const int gx = ks * 8 + 2 * g;
      const i32x4 p0 = *(const i32x4*)(base + (((gx    ) ^ l15) << 4));
      const i32x4 p1 = *(const i32x4*)(base + (((gx + 1) ^ l15) << 4));
      afr[ks][mi] = __builtin_shufflevector(p0, p1, 0, 1, 2, 3, 4, 5, 6, 7);
    }

  const float NEG = __uint_as_float(0xFF800000u);  // -inf
  float rs1[4][4], rs2[4][4];
  #pragma unroll
  for (int mi = 0; mi < 4; ++mi)
    #pragma unroll
    for (int rg = 0; rg < 4; ++rg) { rs1[mi][rg] = NEG; rs2[mi][rg] = NEG; }

  for (int mt = 0; mt < MT_ITERS; ++mt) {
    f32x4 acc[4][4];
    #pragma unroll
    for (int mi = 0; mi < 4; ++mi)
      #pragma unroll
      for (int ni = 0; ni < 4; ++ni) acc[mi][ni] = (f32x4){0.f, 0.f, 0.f, 0.f};

    #pragma unroll
    for (int ks = 0; ks < 2; ++ks) {
      const int s = mt * 2 + ks;
      if (s > 0) {
        __syncthreads();                   // prev Bs readers done
        const int src = (s >> 1) * BNT * D_ + (s & 1) * 128;
        #pragma unroll
        for (int i = 0; i < 4; ++i)
          glds16(Bb + src + offB + i * 8192, (char*)Bs + lds0 + i * 4096);
        __syncthreads();                   // Bs ready (vmcnt(0) lockstep spring)
      }
      #pragma unroll
      for (int ni = 0; ni < 4; ++ni) {
        const int row = wn * 64 + ni * 16 + l15;  // row & 7 == l15 & 7
        const uchar* base = Bs + row * 128;
        const int gx = 2 * g;
        const i32x4 p0 = *(const i32x4*)(base + (((gx    ) ^ (l15 & 7)) << 4));
        const i32x4 p1 = *(const i32x4*)(base + (((gx + 1) ^ (l15 & 7)) << 4));
        const i32x8 bf = __builtin_shufflevector(p0, p1, 0, 1, 2, 3, 4, 5, 6, 7);
        __builtin_amdgcn_s_setprio(1);
        #pragma unroll
        for (int mi = 0; mi < 4; ++mi)
          acc[mi][ni] = __builtin_amdgcn_mfma_scale_f32_16x16x128_f8f6f4(
              afr[ks][mi], bf, acc[mi][ni], 0, 0, 0, 127, 0, 127);
        __builtin_amdgcn_s_setprio(0);
      }
    }

    // ---- row-direction fold (state persists across mt) ----
    const int colb = mt * BNT + wn * 64;     // scan-local col base for this wave
    #pragma unroll
    for (int ni = 0; ni < 4; ++ni) {
      const uint tagc = (uint)(1023 - (colb + ni * 16 + l15));
      #pragma unroll
      for (int mi = 0; mi < 4; ++mi)
        #pragma unroll
        for (int rg = 0; rg < 4; ++rg)
          top2(rs1[mi][rg], rs2[mi][rg], packkey(acc[mi][ni][rg], 0xFFFFFC00u, tagc));
    }

    // ---- col-direction fold (per-tile; 6-bit inv row tag over wm's 64 rows) ----
    const uint tgb = (uint)(63 - g * 4);
    #pragma unroll
    for (int ni = 0; ni < 4; ++ni) {
      float c1 = NEG, c2 = NEG;
      #pragma unroll
      for (int mi = 0; mi < 4; ++mi)
        #pragma unroll
        for (int rg = 0; rg < 4; ++rg)
          top2(c1, c2, packkey(acc[mi][ni][rg], 0xFFFFFFC0u, tgb - (uint)(mi * 16 + rg)));
      #pragma unroll
      for (int off = 16; off <= 32; off <<= 1) {
        const float o1 = __shfl_xor(c1, off);
        const float o2 = __shfl_xor(c2, off);
        top2merge(c1, c2, o1, o2);
      }
      if (g == 0)
        partC[((size_t)(rb * 2 + wm) * B_ + b) * N_ + c0 + colb + ni * 16 + l15] =
            make_uint2(__float_as_uint(c1), __float_as_uint(c2));
    }
  }

  // ---- row merge across 16 column-lanes, write per-(cs,wn) partials ----
  #pragma unroll
  for (int off = 1; off < 16; off <<= 1) {
    #pragma unroll
    for (int mi = 0; mi < 4; ++mi)
      #pragma unroll
      for (int rg = 0; rg < 4; ++rg) {
        const float o1 = __shfl_xor(rs1[mi][rg], off);
        const float o2 = __shfl_xor(rs2[mi][rg], off);
        top2merge(rs1[mi][rg], rs2[mi][rg], o1, o2);
      }
  }
  if (l15 == 0) {
    #pragma unroll
    for (int mi = 0; mi < 4; ++mi)
      #pragma unroll
      for (int rg = 0; rg < 4; ++rg)
        partR[((size_t)(cs * 2 + wn) * B_ + b) * N_ + r0 + wm * 64 + mi * 16 + g * 4 + rg] =
            make_uint2(__float_as_uint(rs1[mi][rg]), __float_as_uint(rs2[mi][rg]));
  }
}

// ---- fold partials, decode, ratio test ----
__global__ __launch_bounds__(256)
void merge_kernel(const uint2* __restrict__ pR, const uint2* __restrict__ pC,
                  int* __restrict__ m0, float* __restrict__ s0, int* __restrict__ m1)
{
  const int tid = blockIdx.x * 256 + threadIdx.x;
  if (tid >= 2 * B_ * N_) return;
  const int dir = tid >> 15;
  const int i = tid & (B_ * N_ - 1);
  const float NEG = __uint_as_float(0xFF800000u);

  if (dir == 0) {
    float s1 = NEG, s2 = NEG; int bs = 0;
    #pragma unroll
    for (int sl = 0; sl < 8; ++sl) {
      const uint2 v = pR[(size_t)sl * B_ * N_ + i];
      const float o1 = __uint_as_float(v.x), o2 = __uint_as_float(v.y);
      bs = (o1 > s1) ? sl : bs;
      top2merge(s1, s2, o1, o2);
    }
    const uint k1 = __float_as_uint(s1);
    const int col = (bs >> 1) * 1024 + 1023 - (int)(k1 & 0x3FFu);
    const float v1 = __uint_as_float(k1 & 0xFFFFFC00u);
    const float v2 = __uint_as_float(__float_as_uint(s2) & 0xFFFFFC00u);
    const bool ok = (1.0f - v1) <= 0.64f * (1.0f - v2);   // Lowe 0.8^2
    m0[i] = ok ? col : -1;
    s0[i] = ok ? (v1 + 1.0f) * 0.5f : 0.0f;
  } else {
    float s1 = NEG, s2 = NEG; int bs = 0;
    #pragma unroll 8
    for (int sl = 0; sl < 64; ++sl) {
      const uint2 v = pC[(size_t)sl * B_ * N_ + i];
      const float o1 = __uint_as_float(v.x), o2 = __uint_as_float(v.y);
      bs = (o1 > s1) ? sl : bs;
      top2merge(s1, s2, o1, o2);
    }
    const uint k1 = __float_as_uint(s1);
    const int row = bs * 64 + 63 - (int)(k1 & 0x3Fu);
    const float v1 = __uint_as_float(k1 & 0xFFFFFFC0u);
    const float v2 = __uint_as_float(__float_as_uint(s2) & 0xFFFFFFC0u);
    const bool ok = (1.0f - v1) <= 0.64f * (1.0f - v2);
    m1[i] = ok ? row : -1;
  }
}

// ---- mutual check + output ----
__global__ __launch_bounds__(256)
void finalize_kernel(const int* __restrict__ m0, const float* __restrict__ s0,
                     const int* __restrict__ m1, float* __restrict__ out)
{
  const int idx = blockIdx.x * 256 + threadIdx.x;
  if (idx >= B_ * N_) return;
  const int b = idx >> 12;
  const int n = idx & (N_ - 1);
  const int mm = m0[idx];
  int res = -1;
  if (mm > -1 && m1[((size_t)b << 12) + mm] == n) res = mm;
  out[idx] = (float)res;
  out[B_ * N_ + idx] = s0[idx];
}

extern "C" void kernel_launch(void* const* d_in, const int* in_sizes, int n_in,
                              void* d_out, int out_size, void* d_ws, size_t ws_size,
                              hipStream_t stream)
{
  const float* d0 = (const float*)d_in[0];
  const float* d1 = (const float*)d_in[1];
  float* out = (float*)d_out;

  uchar* At = (uchar*)((char*)d_ws + OFF_AT);
  uchar* Bt = (uchar*)((char*)d_ws + OFF_BT);
  uint2* PR = (uint2*)((char*)d_ws + OFF_PR);
  uint2* PC = (uint2*)((char*)d_ws + OFF_PC);
  int*   m0 = (int*)  ((char*)d_ws + OFF_M0);
  float* s0 = (float*)((char*)d_ws + OFF_S0);
  int*   m1 = (int*)  ((char*)d_ws + OFF_M1);

  prep_kernel<<<dim3(N_ / 32, D_ / 32, 16), 256, 0, stream>>>(d0, d1, At, Bt);
  nn_pass<<<dim3(B_ * (N_ / BMR) * CSPLIT), 256, 0, stream>>>(At, Bt, PR, PC);
  merge_kernel<<<dim3(2 * B_ * N_ / 256), 256, 0, stream>>>(PR, PC, m0, s0, m1);
  finalize_kernel<<<dim3(B_ * N_ / 256), 256, 0, stream>>>(m0, s0, m1, out);
}

// Round 7
// 86.878 us; speedup vs baseline: 1.9279x; 1.1566x over previous
//
#include <hip/hip_runtime.h>

// NearestNeighbor b=8, d=256, n=m=4096.
// Round 7: MX-fp8 K=128, A LDS-resident (no reg hoist), double-buffered B with
// T3-min single-barrier halves, CSPLIT=2, pairwise med3/max3 top-2 folds.

typedef unsigned int uint;
typedef unsigned char uchar;
typedef int i32x4 __attribute__((ext_vector_type(4)));
typedef int i32x8 __attribute__((ext_vector_type(8)));
typedef float f32x4 __attribute__((ext_vector_type(4)));

constexpr int B_ = 8, D_ = 256, N_ = 4096;
constexpr int BMR = 128;                       // rows per block
constexpr int BNT = 128;                       // cols per tile iteration
constexpr int CSPLIT = 2;                      // column split
constexpr int MT_ITERS = (N_ / CSPLIT) / BNT;  // 16
constexpr int NSTAGES = MT_ITERS * 2;          // 32 half-stages (K = 2 x 128)

// workspace layout (bytes)
constexpr size_t SZ_PANEL = (size_t)B_ * N_ * D_;        // 8.39 MB (fp8)
constexpr size_t OFF_AT = 0;
constexpr size_t OFF_BT = SZ_PANEL;
constexpr size_t OFF_PR = 2 * SZ_PANEL;                  // row partials: 4 slots
constexpr size_t SZ_PR  = (size_t)4 * B_ * N_ * 8;       // 1 MB
constexpr size_t OFF_PC = OFF_PR + SZ_PR;                // col partials: 64 slots
constexpr size_t SZ_PC  = (size_t)64 * B_ * N_ * 8;      // 16.8 MB
constexpr size_t OFF_M0 = OFF_PC + SZ_PC;
constexpr size_t OFF_S0 = OFF_M0 + (size_t)B_ * N_ * 4;
constexpr size_t OFF_M1 = OFF_S0 + (size_t)B_ * N_ * 4;

// f32 -> OCP e4m3fn (RNE, saturating). Inputs here are in [-1,1].
__device__ __forceinline__ uchar f2e4m3(float f) {
  uint u = __float_as_uint(f);
  uint s = (u >> 24) & 0x80u;
  uint mag = u & 0x7FFFFFFFu;
  if (mag >= 0x43E00000u) return (uchar)(s | 0x7Eu);       // clamp to ±448
  int e = (int)(mag >> 23) - 127;
  if (e >= -6) {                                            // normal range
    uint m = (mag >> 20) & 7u;
    uint rem = mag & 0xFFFFFu;
    m += (rem > 0x80000u) || (rem == 0x80000u && (m & 1u));
    uint ef = (uint)(e + 7);
    if (m == 8u) { m = 0u; ef += 1u; }
    if (ef >= 16u) return (uchar)(s | 0x7Eu);
    return (uchar)(s | (ef << 3) | m);
  } else {                                                  // subnormal: RNE(|f|*512)
    int q = __float2int_rn(__uint_as_float(mag) * 512.0f);
    if (q >= 8) return (uchar)(s | 0x08u);
    return (uchar)(s | (uint)q);
  }
}

__device__ __forceinline__ void glds16(const void* g, void* l) {
  __builtin_amdgcn_global_load_lds(
      (const __attribute__((address_space(1))) void*)(uintptr_t)(g),
      (__attribute__((address_space(3))) void*)(uint32_t)(uintptr_t)(l),
      16, 0, 0);
}

__device__ __forceinline__ float packkey(float v, uint mask, uint tag) {
  return __uint_as_float((__float_as_uint(v) & mask) | tag);   // v_and_or_b32
}

__device__ __forceinline__ float med3f(float a, float b, float c) {
#if __has_builtin(__builtin_amdgcn_fmed3f)
  return __builtin_amdgcn_fmed3f(a, b, c);
#else
  return fmaxf(fminf(a, b), fminf(fmaxf(a, b), c));
#endif
}

// top-2 update with TWO new keys; invariant s1 >= s2.
// second(union) = max(s2, med3(s1,k0,k1)); first = max3(s1,k0,k1).
__device__ __forceinline__ void top2p(float& s1, float& s2, float k0, float k1) {
  const float mid = med3f(s1, k0, k1);
  s1 = fmaxf(fmaxf(s1, k0), k1);     // fuses to v_max3_f32
  s2 = fmaxf(s2, mid);
}

// merge two sorted top-2 pairs
__device__ __forceinline__ void top2merge(float& s1, float& s2, float o1, float o2) {
  const float lo = fminf(s1, o1);
  s1 = fmaxf(s1, o1);
  s2 = fmaxf(lo, fmaxf(s2, o2));
}

// ---- transpose + convert: [b][256][4096] f32 -> [b][4096][256] e4m3 ----
__global__ __launch_bounds__(256)
void prep_kernel(const float* __restrict__ in0, const float* __restrict__ in1,
                 uchar* __restrict__ At, uchar* __restrict__ Bt)
{
  __shared__ uchar tile[32][36];
  const int z = blockIdx.z;
  const float* src = (z < 8) ? in0 : in1;
  uchar* dst = (z < 8) ? At : Bt;
  const int b = z & 7;
  const int k0 = blockIdx.y * 32, n0 = blockIdx.x * 32;
  const int t = threadIdx.x;
  const int kl = t >> 3, n4 = (t & 7) * 4;
  const float4 v = *(const float4*)(src + ((size_t)b * D_ + k0 + kl) * N_ + n0 + n4);
  tile[kl][n4 + 0] = f2e4m3(v.x); tile[kl][n4 + 1] = f2e4m3(v.y);
  tile[kl][n4 + 2] = f2e4m3(v.z); tile[kl][n4 + 3] = f2e4m3(v.w);
  __syncthreads();
  const int nl = t >> 3, k4 = (t & 7) * 4;
  uchar4 o;
  o.x = tile[k4 + 0][nl]; o.y = tile[k4 + 1][nl];
  o.z = tile[k4 + 2][nl]; o.w = tile[k4 + 3][nl];
  *(uchar4*)(dst + ((size_t)b * N_ + n0 + nl) * D_ + k0 + k4) = o;
}

// ---- fused GEMM (MX-fp8 K=128) + dual-direction top-2, pipelined ----
// Block: 128 rows x 2048-col scan. 4 waves 2Mx2N: wave (wm,wn) = 64x64 of tile.
// Row keys: 21 bits | 11-bit inv col tag. Col keys: 26 bits | 6-bit inv row tag.
__global__ __launch_bounds__(256, 2)
void nn_pass(const uchar* __restrict__ A, const uchar* __restrict__ Bp,
             uint2* __restrict__ partR, uint2* __restrict__ partC)
{
  __shared__ uchar As[BMR * 256];      // 32 KB, full K, kernel-resident
  __shared__ uchar Bs[2][BNT * 128];   // 2 x 16 KB double buffer

  const int t = threadIdx.x;
  const int bid = blockIdx.x;
  const int b = bid & 7;                   // XCD-pinned batch
  const int rb = (bid >> 3) & 31;
  const int cs = bid >> 8;                 // 0..1
  const size_t bOff = (size_t)b * N_ * D_;
  const int r0 = rb * BMR;
  const int c0 = cs * (N_ / CSPLIT);

  const int l = t & 63, wid = t >> 6, wm = wid >> 1, wn = wid & 1;
  const int l15 = l & 15, g = l >> 4;

  // staging addressing (pre-swizzled global source, linear LDS dest)
  const int offA = (t >> 4) * D_ + ((((t & 15) ^ (t >> 4)) & 15) << 4);
  const int offB = (t >> 3) * D_ + ((((t & 7) ^ ((t >> 3) & 7))) << 4);
  const int lds0 = t * 16;

  const uchar* Ab = A  + bOff + (size_t)r0 * D_;
  const uchar* Bb = Bp + bOff + (size_t)c0 * D_;

  // ---- prologue: full-K A tile + B half-stage 0 ----
  #pragma unroll
  for (int i = 0; i < 8; ++i)
    glds16(Ab + offA + i * 4096, (char*)As + lds0 + i * 4096);
  #pragma unroll
  for (int i = 0; i < 4; ++i)
    glds16(Bb + offB + i * 8192, (char*)Bs[0] + lds0 + i * 4096);
  __syncthreads();

  const float NEG = __uint_as_float(0xFF800000u);  // -inf
  float rs1[4][4], rs2[4][4];
  #pragma unroll
  for (int mi = 0; mi < 4; ++mi)
    #pragma unroll
    for (int rg = 0; rg < 4; ++rg) { rs1[mi][rg] = NEG; rs2[mi][rg] = NEG; }

  float cp1[4], cp2[4];   // previous mt's col partials (stored post-barrier)

  #pragma unroll 1
  for (int mt = 0; mt < MT_ITERS; ++mt) {
    // store prev col partials (issued just after a barrier -> drained 1 half later)
    if (mt > 0 && g == 0) {
      const int cbp = (mt - 1) * BNT + wn * 64;
      #pragma unroll
      for (int ni = 0; ni < 4; ++ni)
        partC[((size_t)(rb * 2 + wm) * B_ + b) * N_ + c0 + cbp + ni * 16 + l15] =
            make_uint2(__float_as_uint(cp1[ni]), __float_as_uint(cp2[ni]));
    }

    f32x4 acc[4][4];
    #pragma unroll
    for (int mi = 0; mi < 4; ++mi)
      #pragma unroll
      for (int ni = 0; ni < 4; ++ni) acc[mi][ni] = (f32x4){0.f, 0.f, 0.f, 0.f};

    #pragma unroll
    for (int ks = 0; ks < 2; ++ks) {
      const int s = mt * 2 + ks;
      // issue next half-stage's B loads into the other buffer
      if (s + 1 < NSTAGES) {
        const int src = ((s + 1) >> 1) * BNT * D_ + ((s + 1) & 1) * 128;
        #pragma unroll
        for (int i = 0; i < 4; ++i)
          glds16(Bb + src + offB + i * 8192, (char*)Bs[(s + 1) & 1] + lds0 + i * 4096);
      }

      // fragment reads (compiler-managed lgkmcnt)
      i32x8 af[4], bf[4];
      #pragma unroll
      for (int mi = 0; mi < 4; ++mi) {
        const uchar* base = As + (wm * 64 + mi * 16 + l15) * 256;
        const int gx = ks * 8 + 2 * g;
        const i32x4 p0 = *(const i32x4*)(base + (((gx    ) ^ l15) << 4));
        const i32x4 p1 = *(const i32x4*)(base + (((gx + 1) ^ l15) << 4));
        af[mi] = __builtin_shufflevector(p0, p1, 0, 1, 2, 3, 4, 5, 6, 7);
      }
      #pragma unroll
      for (int ni = 0; ni < 4; ++ni) {
        const uchar* base = (const uchar*)Bs[s & 1] + (wn * 64 + ni * 16 + l15) * 128;
        const int gx = 2 * g;
        const i32x4 p0 = *(const i32x4*)(base + (((gx    ) ^ (l15 & 7)) << 4));
        const i32x4 p1 = *(const i32x4*)(base + (((gx + 1) ^ (l15 & 7)) << 4));
        bf[ni] = __builtin_shufflevector(p0, p1, 0, 1, 2, 3, 4, 5, 6, 7);
      }

      __builtin_amdgcn_s_setprio(1);
      #pragma unroll
      for (int mi = 0; mi < 4; ++mi)
        #pragma unroll
        for (int ni = 0; ni < 4; ++ni)
          acc[mi][ni] = __builtin_amdgcn_mfma_scale_f32_16x16x128_f8f6f4(
              af[mi], bf[ni], acc[mi][ni], 0, 0, 0, 127, 0, 127);
      __builtin_amdgcn_s_setprio(0);

      if (ks == 1) {
        // ---- FOLD (covers the drain of this half's STAGE before syncthreads) ----
        // row direction (persistent rs state)
        const int colb = mt * BNT + wn * 64;
        const uint tg0 = (uint)(2047 - (colb + l15));
        #pragma unroll
        for (int mi = 0; mi < 4; ++mi)
          #pragma unroll
          for (int rg = 0; rg < 4; ++rg) {
            const float k0 = packkey(acc[mi][0][rg], 0xFFFFF800u, tg0);
            const float k1 = packkey(acc[mi][1][rg], 0xFFFFF800u, tg0 - 16);
            const float k2 = packkey(acc[mi][2][rg], 0xFFFFF800u, tg0 - 32);
            const float k3 = packkey(acc[mi][3][rg], 0xFFFFF800u, tg0 - 48);
            top2p(rs1[mi][rg], rs2[mi][rg], k0, k1);
            top2p(rs1[mi][rg], rs2[mi][rg], k2, k3);
          }
        // col direction (per-tile, merged across quarter groups)
        const uint tgb = (uint)(63 - g * 4);
        #pragma unroll
        for (int ni = 0; ni < 4; ++ni) {
          float c1 = NEG, c2 = NEG;
          #pragma unroll
          for (int mi = 0; mi < 4; ++mi) {
            const float k0 = packkey(acc[mi][ni][0], 0xFFFFFFC0u, tgb - (uint)(mi * 16));
            const float k1 = packkey(acc[mi][ni][1], 0xFFFFFFC0u, tgb - (uint)(mi * 16 + 1));
            const float k2 = packkey(acc[mi][ni][2], 0xFFFFFFC0u, tgb - (uint)(mi * 16 + 2));
            const float k3 = packkey(acc[mi][ni][3], 0xFFFFFFC0u, tgb - (uint)(mi * 16 + 3));
            top2p(c1, c2, k0, k1);
            top2p(c1, c2, k2, k3);
          }
          #pragma unroll
          for (int off = 16; off <= 32; off <<= 1) {
            const float o1 = __shfl_xor(c1, off);
            const float o2 = __shfl_xor(c2, off);
            top2merge(c1, c2, o1, o2);
          }
          cp1[ni] = c1; cp2[ni] = c2;
        }
      }
      __syncthreads();   // single barrier per half-stage (vmcnt+lgkm drain inside)
    }
  }

  // final col-partial store (mt = MT_ITERS-1)
  if (g == 0) {
    const int cbp = (MT_ITERS - 1) * BNT + wn * 64;
    #pragma unroll
    for (int ni = 0; ni < 4; ++ni)
      partC[((size_t)(rb * 2 + wm) * B_ + b) * N_ + c0 + cbp + ni * 16 + l15] =
          make_uint2(__float_as_uint(cp1[ni]), __float_as_uint(cp2[ni]));
  }

  // ---- row merge across 16 column-lanes, write per-(cs,wn) partials ----
  #pragma unroll
  for (int off = 1; off < 16; off <<= 1) {
    #pragma unroll
    for (int mi = 0; mi < 4; ++mi)
      #pragma unroll
      for (int rg = 0; rg < 4; ++rg) {
        const float o1 = __shfl_xor(rs1[mi][rg], off);
        const float o2 = __shfl_xor(rs2[mi][rg], off);
        top2merge(rs1[mi][rg], rs2[mi][rg], o1, o2);
      }
  }
  if (l15 == 0) {
    #pragma unroll
    for (int mi = 0; mi < 4; ++mi)
      #pragma unroll
      for (int rg = 0; rg < 4; ++rg)
        partR[((size_t)(cs * 2 + wn) * B_ + b) * N_ + r0 + wm * 64 + mi * 16 + g * 4 + rg] =
            make_uint2(__float_as_uint(rs1[mi][rg]), __float_as_uint(rs2[mi][rg]));
  }
}

// ---- fold partials, decode, ratio test ----
__global__ __launch_bounds__(256)
void merge_kernel(const uint2* __restrict__ pR, const uint2* __restrict__ pC,
                  int* __restrict__ m0, float* __restrict__ s0, int* __restrict__ m1)
{
  const int tid = blockIdx.x * 256 + threadIdx.x;
  if (tid >= 2 * B_ * N_) return;
  const int dir = tid >> 15;
  const int i = tid & (B_ * N_ - 1);
  const float NEG = __uint_as_float(0xFF800000u);

  if (dir == 0) {
    float s1 = NEG, s2 = NEG; int bs = 0;
    #pragma unroll
    for (int sl = 0; sl < 4; ++sl) {
      const uint2 v = pR[(size_t)sl * B_ * N_ + i];
      const float o1 = __uint_as_float(v.x), o2 = __uint_as_float(v.y);
      bs = (o1 > s1) ? sl : bs;
      top2merge(s1, s2, o1, o2);
    }
    const uint k1 = __float_as_uint(s1);
    const int col = (bs >> 1) * 2048 + 2047 - (int)(k1 & 0x7FFu);
    const float v1 = __uint_as_float(k1 & 0xFFFFF800u);
    const float v2 = __uint_as_float(__float_as_uint(s2) & 0xFFFFF800u);
    const bool ok = (1.0f - v1) <= 0.64f * (1.0f - v2);   // Lowe 0.8^2
    m0[i] = ok ? col : -1;
    s0[i] = ok ? (v1 + 1.0f) * 0.5f : 0.0f;
  } else {
    float s1 = NEG, s2 = NEG; int bs = 0;
    #pragma unroll 8
    for (int sl = 0; sl < 64; ++sl) {
      const uint2 v = pC[(size_t)sl * B_ * N_ + i];
      const float o1 = __uint_as_float(v.x), o2 = __uint_as_float(v.y);
      bs = (o1 > s1) ? sl : bs;
      top2merge(s1, s2, o1, o2);
    }
    const uint k1 = __float_as_uint(s1);
    const int row = bs * 64 + 63 - (int)(k1 & 0x3Fu);
    const float v1 = __uint_as_float(k1 & 0xFFFFFFC0u);
    const float v2 = __uint_as_float(__float_as_uint(s2) & 0xFFFFFFC0u);
    const bool ok = (1.0f - v1) <= 0.64f * (1.0f - v2);
    m1[i] = ok ? row : -1;
  }
}

// ---- mutual check + output ----
__global__ __launch_bounds__(256)
void finalize_kernel(const int* __restrict__ m0, const float* __restrict__ s0,
                     const int* __restrict__ m1, float* __restrict__ out)
{
  const int idx = blockIdx.x * 256 + threadIdx.x;
  if (idx >= B_ * N_) return;
  const int b = idx >> 12;
  const int n = idx & (N_ - 1);
  const int mm = m0[idx];
  int res = -1;
  if (mm > -1 && m1[((size_t)b << 12) + mm] == n) res = mm;
  out[idx] = (float)res;
  out[B_ * N_ + idx] = s0[idx];
}

extern "C" void kernel_launch(void* const* d_in, const int* in_sizes, int n_in,
                              void* d_out, int out_size, void* d_ws, size_t ws_size,
                              hipStream_t stream)
{
  const float* d0 = (const float*)d_in[0];
  const float* d1 = (const float*)d_in[1];
  float* out = (float*)d_out;

  uchar* At = (uchar*)((char*)d_ws + OFF_AT);
  uchar* Bt = (uchar*)((char*)d_ws + OFF_BT);
  uint2* PR = (uint2*)((char*)d_ws + OFF_PR);
  uint2* PC = (uint2*)((char*)d_ws + OFF_PC);
  int*   m0 = (int*)  ((char*)d_ws + OFF_M0);
  float* s0 = (float*)((char*)d_ws + OFF_S0);
  int*   m1 = (int*)  ((char*)d_ws + OFF_M1);

  prep_kernel<<<dim3(N_ / 32, D_ / 32, 16), 256, 0, stream>>>(d0, d1, At, Bt);
  nn_pass<<<dim3(B_ * (N_ / BMR) * CSPLIT), 256, 0, stream>>>(At, Bt, PR, PC);
  merge_kernel<<<dim3(2 * B_ * N_ / 256), 256, 0, stream>>>(PR, PC, m0, s0, m1);
  finalize_kernel<<<dim3(B_ * N_ / 256), 256, 0, stream>>>(m0, s0, m1, out);
}

// Round 8
// 81.703 us; speedup vs baseline: 2.0500x; 1.0633x over previous
//
#include <hip/hip_runtime.h>

// NearestNeighbor b=8, d=256, n=m=4096.
// Round 8: frag-tiled fp8 panels (prep writes MFMA-fragment order).
// nn_pass: A-frags in registers (global coalesced loads), LDS = B dbuf only,
// all ds_reads lane-linear with immediate offsets (0 conflicts, 0 addr VALU).

typedef unsigned int uint;
typedef unsigned char uchar;
typedef int i32x4 __attribute__((ext_vector_type(4)));
typedef int i32x8 __attribute__((ext_vector_type(8)));
typedef float f32x4 __attribute__((ext_vector_type(4)));

constexpr int B_ = 8, D_ = 256, N_ = 4096;
constexpr int BMR = 128;                       // rows per block
constexpr int BNT = 128;                       // cols per tile iteration
constexpr int CSPLIT = 2;                      // column split
constexpr int MT_ITERS = (N_ / CSPLIT) / BNT;  // 16

// Unified frag-tiled panel layout (per batch, 1 MB):
// element (n,k): seg=n>>7, q=(n>>6)&1, r4=(n>>4)&3, i16=n&15;
//               ks=k>>7, g=(k>>5)&3, h=(k>>4)&1, kb=k&15
// off = seg*32768 + ks*16384 + ((q*4+r4)*2+h)*1024 + (g*16+i16)*16 + kb

// workspace layout (bytes)
constexpr size_t SZ_PANEL = (size_t)B_ * N_ * D_;        // 8.39 MB (fp8)
constexpr size_t OFF_AT = 0;
constexpr size_t OFF_BT = SZ_PANEL;
constexpr size_t OFF_PR = 2 * SZ_PANEL;                  // row partials: 4 slots
constexpr size_t SZ_PR  = (size_t)4 * B_ * N_ * 8;       // 1 MB
constexpr size_t OFF_PC = OFF_PR + SZ_PR;                // col partials: 64 slots
constexpr size_t SZ_PC  = (size_t)64 * B_ * N_ * 8;      // 16.8 MB
constexpr size_t OFF_M0 = OFF_PC + SZ_PC;
constexpr size_t OFF_S0 = OFF_M0 + (size_t)B_ * N_ * 4;
constexpr size_t OFF_M1 = OFF_S0 + (size_t)B_ * N_ * 4;

// f32 -> OCP e4m3fn (RNE, saturating).
__device__ __forceinline__ uchar f2e4m3(float f) {
  uint u = __float_as_uint(f);
  uint s = (u >> 24) & 0x80u;
  uint mag = u & 0x7FFFFFFFu;
  if (mag >= 0x43E00000u) return (uchar)(s | 0x7Eu);
  int e = (int)(mag >> 23) - 127;
  if (e >= -6) {
    uint m = (mag >> 20) & 7u;
    uint rem = mag & 0xFFFFFu;
    m += (rem > 0x80000u) || (rem == 0x80000u && (m & 1u));
    uint ef = (uint)(e + 7);
    if (m == 8u) { m = 0u; ef += 1u; }
    if (ef >= 16u) return (uchar)(s | 0x7Eu);
    return (uchar)(s | (ef << 3) | m);
  } else {
    int q = __float2int_rn(__uint_as_float(mag) * 512.0f);
    if (q >= 8) return (uchar)(s | 0x08u);
    return (uchar)(s | (uint)q);
  }
}

__device__ __forceinline__ void glds16(const void* g, void* l) {
  __builtin_amdgcn_global_load_lds(
      (const __attribute__((address_space(1))) void*)(uintptr_t)(g),
      (__attribute__((address_space(3))) void*)(uint32_t)(uintptr_t)(l),
      16, 0, 0);
}

__device__ __forceinline__ float packkey(float v, uint mask, uint tag) {
  return __uint_as_float((__float_as_uint(v) & mask) | tag);
}

__device__ __forceinline__ float med3f(float a, float b, float c) {
#if __has_builtin(__builtin_amdgcn_fmed3f)
  return __builtin_amdgcn_fmed3f(a, b, c);
#else
  return fmaxf(fminf(a, b), fminf(fmaxf(a, b), c));
#endif
}

__device__ __forceinline__ void top2p(float& s1, float& s2, float k0, float k1) {
  const float mid = med3f(s1, k0, k1);
  s1 = fmaxf(fmaxf(s1, k0), k1);
  s2 = fmaxf(s2, mid);
}

__device__ __forceinline__ void top2merge(float& s1, float& s2, float o1, float o2) {
  const float lo = fminf(s1, o1);
  s1 = fmaxf(s1, o1);
  s2 = fmaxf(lo, fmaxf(s2, o2));
}

// ---- prep: [b][256][4096] f32 -> frag-tiled fp8 panel ----
// Block: 128 n x 32 k. Phase1: coalesced f32 reads + 4x4 reg micro-transpose
// -> LDS [128][44] fp8. Phase2: emit 256 16B chunks at frag-tiled offsets.
__global__ __launch_bounds__(256)
void prep_kernel(const float* __restrict__ in0, const float* __restrict__ in1,
                 uchar* __restrict__ At, uchar* __restrict__ Bt)
{
  __shared__ uchar tile[128][44];
  const int bz = blockIdx.z;
  const float* src = (bz < 8) ? in0 : in1;
  uchar* dst = (bz < 8) ? At : Bt;
  const int b = bz & 7;
  const int n0 = blockIdx.x * 128;
  const int k0b = blockIdx.y * 32;
  const int t = threadIdx.x;

  const int kq = t >> 5;            // k-quad 0..7 (k-local = kq*4+j)
  const int n4 = (t & 31) * 4;
  const float* pin = src + ((size_t)b * D_ + k0b + kq * 4) * N_ + n0 + n4;
  float4 v[4];
  #pragma unroll
  for (int j = 0; j < 4; ++j) v[j] = *(const float4*)(pin + (size_t)j * N_);
  #pragma unroll
  for (int i = 0; i < 4; ++i) {
    uchar4 o = make_uchar4(f2e4m3(((const float*)&v[0])[i]),
                           f2e4m3(((const float*)&v[1])[i]),
                           f2e4m3(((const float*)&v[2])[i]),
                           f2e4m3(((const float*)&v[3])[i]));
    *(uchar4*)&tile[n4 + i][kq * 4] = o;   // along-k 4B, [n][44] pad -> spread banks
  }
  __syncthreads();

  const int nl = t & 127, h = t >> 7;
  const int kg = k0b + h * 16;                      // global k of this 16B chunk
  const int ks = kg >> 7, g = (kg >> 5) & 3, hh = (kg >> 4) & 1;
  const int q = (nl >> 6) & 1, r4 = (nl >> 4) & 3, i16 = nl & 15;
  i32x4 val;
  #pragma unroll
  for (int j = 0; j < 4; ++j)
    val[j] = *(const int*)&tile[nl][h * 16 + j * 4];
  uchar* po = dst + (size_t)b * (N_ * D_) + (size_t)blockIdx.x * 32768 +
              ks * 16384 + ((q * 4 + r4) * 2 + hh) * 1024 + (g * 16 + i16) * 16;
  *(i32x4*)po = val;
}

// ---- fused GEMM (MX-fp8 K=128) + dual-direction top-2 ----
// Block: 128 rows x 2048-col scan. Waves 2Mx2N: (wm,wn) = 64x64 quadrant.
// A-frags in registers; LDS = B double buffer (2x16KB); all ds_reads lane-linear.
__global__ __launch_bounds__(256, 2)
void nn_pass(const uchar* __restrict__ A, const uchar* __restrict__ Bp,
             uint2* __restrict__ partR, uint2* __restrict__ partC)
{
  __shared__ uchar Bs[2][16384];

  const int t = threadIdx.x;
  const int bid = blockIdx.x;
  const int b = bid & 7;                   // XCD-pinned batch
  const int rb = (bid >> 3) & 31;
  const int cs = bid >> 8;                 // 0..1
  const size_t bOff = (size_t)b * (N_ * D_);
  const int r0 = rb * BMR;

  const int l = t & 63, wid = t >> 6, wm = wid >> 1, wn = wid & 1;
  const int l15 = l & 15, g = l >> 4;
  const int lds0 = t * 16;

  const uchar* Aseg = A + bOff + (size_t)rb * 32768;
  const uchar* Bb = Bp + bOff + (size_t)cs * 524288;   // cs half: 16 segs x 32KB

  // prologue: stage B(ct=0,ks=0) into buf0; load A-frags from global (coalesced)
  #pragma unroll
  for (int i = 0; i < 4; ++i)
    glds16(Bb + i * 4096 + lds0, (char*)Bs[0] + i * 4096 + lds0);

  i32x8 af[2][4];
  #pragma unroll
  for (int ks = 0; ks < 2; ++ks)
    #pragma unroll
    for (int mi = 0; mi < 4; ++mi) {
      const uchar* p = Aseg + ks * 16384 + ((wm * 4 + mi) * 2) * 1024 + l * 16;
      const i32x4 lo = *(const i32x4*)p;
      const i32x4 hi = *(const i32x4*)(p + 1024);
      af[ks][mi] = __builtin_shufflevector(lo, hi, 0, 1, 2, 3, 4, 5, 6, 7);
    }
  __syncthreads();

  const float NEG = __uint_as_float(0xFF800000u);  // -inf
  float rs1[4][4], rs2[4][4];
  #pragma unroll
  for (int mi = 0; mi < 4; ++mi)
    #pragma unroll
    for (int rg = 0; rg < 4; ++rg) { rs1[mi][rg] = NEG; rs2[mi][rg] = NEG; }

  float cp1[4], cp2[4];
  const char* aB = (const char*)Bs[0] + l * 16;   // lane-linear base; imm offsets

  #pragma unroll 1
  for (int mt = 0; mt < MT_ITERS; ++mt) {
    const uchar* Bct = Bb + (size_t)mt * 32768;

    // deferred partC store for tile mt-1 (drains across the next barrier)
    if (mt > 0 && g == 0) {
      const int cbp = (mt - 1) * BNT + wn * 64;
      #pragma unroll
      for (int ni = 0; ni < 4; ++ni)
        partC[((size_t)(rb * 2 + wm) * B_ + b) * N_ + cs * 2048 + cbp + ni * 16 + l15] =
            make_uint2(__float_as_uint(cp1[ni]), __float_as_uint(cp2[ni]));
    }

    f32x4 acc[4][4];
    #pragma unroll
    for (int mi = 0; mi < 4; ++mi)
      #pragma unroll
      for (int ni = 0; ni < 4; ++ni) acc[mi][ni] = (f32x4){0.f, 0.f, 0.f, 0.f};

    // ---- half ks=0: read buf0; stage buf1 <- (ct, ks=1) ----
    #pragma unroll
    for (int i = 0; i < 4; ++i)
      glds16(Bct + 16384 + i * 4096 + lds0, (char*)Bs[1] + i * 4096 + lds0);

    #pragma unroll
    for (int ni = 0; ni < 4; ++ni) {
      const int imm = ((wn * 4 + ni) * 2) * 1024;
      const i32x4 lo = *(const i32x4*)(aB + imm);
      const i32x4 hi = *(const i32x4*)(aB + imm + 1024);
      const i32x8 bf = __builtin_shufflevector(lo, hi, 0, 1, 2, 3, 4, 5, 6, 7);
      __builtin_amdgcn_s_setprio(1);
      #pragma unroll
      for (int mi = 0; mi < 4; ++mi)
        acc[mi][ni] = __builtin_amdgcn_mfma_scale_f32_16x16x128_f8f6f4(
            af[0][mi], bf, acc[mi][ni], 0, 0, 0, 127, 0, 127);
      __builtin_amdgcn_s_setprio(0);
    }
    __syncthreads();

    // ---- half ks=1: read buf1; stage buf0 <- (ct+1, ks=0) ----
    if (mt + 1 < MT_ITERS) {
      #pragma unroll
      for (int i = 0; i < 4; ++i)
        glds16(Bct + 32768 + i * 4096 + lds0, (char*)Bs[0] + i * 4096 + lds0);
    }
    #pragma unroll
    for (int ni = 0; ni < 4; ++ni) {
      const int imm = 16384 + ((wn * 4 + ni) * 2) * 1024;
      const i32x4 lo = *(const i32x4*)(aB + imm);
      const i32x4 hi = *(const i32x4*)(aB + imm + 1024);
      const i32x8 bf = __builtin_shufflevector(lo, hi, 0, 1, 2, 3, 4, 5, 6, 7);
      __builtin_amdgcn_s_setprio(1);
      #pragma unroll
      for (int mi = 0; mi < 4; ++mi)
        acc[mi][ni] = __builtin_amdgcn_mfma_scale_f32_16x16x128_f8f6f4(
            af[1][mi], bf, acc[mi][ni], 0, 0, 0, 127, 0, 127);
      __builtin_amdgcn_s_setprio(0);
    }

    // ---- fold: row direction (persistent) ----
    const int colb = mt * BNT + wn * 64;
    const uint tg0 = (uint)(2047 - (colb + l15));
    #pragma unroll
    for (int mi = 0; mi < 4; ++mi)
      #pragma unroll
      for (int rg = 0; rg < 4; ++rg) {
        const float k0 = packkey(acc[mi][0][rg], 0xFFFFF800u, tg0);
        const float k1 = packkey(acc[mi][1][rg], 0xFFFFF800u, tg0 - 16);
        const float k2 = packkey(acc[mi][2][rg], 0xFFFFF800u, tg0 - 32);
        const float k3 = packkey(acc[mi][3][rg], 0xFFFFF800u, tg0 - 48);
        top2p(rs1[mi][rg], rs2[mi][rg], k0, k1);
        top2p(rs1[mi][rg], rs2[mi][rg], k2, k3);
      }
    // ---- fold: col direction (per tile; 6-bit inv row tag over wm's 64 rows) ----
    const uint tgb = (uint)(63 - g * 4);
    #pragma unroll
    for (int ni = 0; ni < 4; ++ni) {
      float c1 = NEG, c2 = NEG;
      #pragma unroll
      for (int mi = 0; mi < 4; ++mi) {
        const float k0 = packkey(acc[mi][ni][0], 0xFFFFFFC0u, tgb - (uint)(mi * 16));
        const float k1 = packkey(acc[mi][ni][1], 0xFFFFFFC0u, tgb - (uint)(mi * 16 + 1));
        const float k2 = packkey(acc[mi][ni][2], 0xFFFFFFC0u, tgb - (uint)(mi * 16 + 2));
        const float k3 = packkey(acc[mi][ni][3], 0xFFFFFFC0u, tgb - (uint)(mi * 16 + 3));
        top2p(c1, c2, k0, k1);
        top2p(c1, c2, k2, k3);
      }
      #pragma unroll
      for (int off = 16; off <= 32; off <<= 1) {
        const float o1 = __shfl_xor(c1, off);
        const float o2 = __shfl_xor(c2, off);
        top2merge(c1, c2, o1, o2);
      }
      cp1[ni] = c1; cp2[ni] = c2;
    }
    __syncthreads();
  }

  // final col-partial store
  if (g == 0) {
    const int cbp = (MT_ITERS - 1) * BNT + wn * 64;
    #pragma unroll
    for (int ni = 0; ni < 4; ++ni)
      partC[((size_t)(rb * 2 + wm) * B_ + b) * N_ + cs * 2048 + cbp + ni * 16 + l15] =
          make_uint2(__float_as_uint(cp1[ni]), __float_as_uint(cp2[ni]));
  }

  // row merge across 16 column-lanes, write per-(cs,wn) partials
  #pragma unroll
  for (int off = 1; off < 16; off <<= 1) {
    #pragma unroll
    for (int mi = 0; mi < 4; ++mi)
      #pragma unroll
      for (int rg = 0; rg < 4; ++rg) {
        const float o1 = __shfl_xor(rs1[mi][rg], off);
        const float o2 = __shfl_xor(rs2[mi][rg], off);
        top2merge(rs1[mi][rg], rs2[mi][rg], o1, o2);
      }
  }
  if (l15 == 0) {
    #pragma unroll
    for (int mi = 0; mi < 4; ++mi)
      #pragma unroll
      for (int rg = 0; rg < 4; ++rg)
        partR[((size_t)(cs * 2 + wn) * B_ + b) * N_ + r0 + wm * 64 + mi * 16 + g * 4 + rg] =
            make_uint2(__float_as_uint(rs1[mi][rg]), __float_as_uint(rs2[mi][rg]));
  }
}

// ---- fold partials, decode, ratio test ----
__global__ __launch_bounds__(256)
void merge_kernel(const uint2* __restrict__ pR, const uint2* __restrict__ pC,
                  int* __restrict__ m0, float* __restrict__ s0, int* __restrict__ m1)
{
  const int tid = blockIdx.x * 256 + threadIdx.x;
  if (tid >= 2 * B_ * N_) return;
  const int dir = tid >> 15;
  const int i = tid & (B_ * N_ - 1);
  const float NEG = __uint_as_float(0xFF800000u);

  if (dir == 0) {
    float s1 = NEG, s2 = NEG; int bs = 0;
    #pragma unroll
    for (int sl = 0; sl < 4; ++sl) {
      const uint2 v = pR[(size_t)sl * B_ * N_ + i];
      const float o1 = __uint_as_float(v.x), o2 = __uint_as_float(v.y);
      bs = (o1 > s1) ? sl : bs;
      top2merge(s1, s2, o1, o2);
    }
    const uint k1 = __float_as_uint(s1);
    const int col = (bs >> 1) * 2048 + 2047 - (int)(k1 & 0x7FFu);
    const float v1 = __uint_as_float(k1 & 0xFFFFF800u);
    const float v2 = __uint_as_float(__float_as_uint(s2) & 0xFFFFF800u);
    const bool ok = (1.0f - v1) <= 0.64f * (1.0f - v2);   // Lowe 0.8^2
    m0[i] = ok ? col : -1;
    s0[i] = ok ? (v1 + 1.0f) * 0.5f : 0.0f;
  } else {
    float s1 = NEG, s2 = NEG; int bs = 0;
    #pragma unroll 8
    for (int sl = 0; sl < 64; ++sl) {
      const uint2 v = pC[(size_t)sl * B_ * N_ + i];
      const float o1 = __uint_as_float(v.x), o2 = __uint_as_float(v.y);
      bs = (o1 > s1) ? sl : bs;
      top2merge(s1, s2, o1, o2);
    }
    const uint k1 = __float_as_uint(s1);
    const int row = bs * 64 + 63 - (int)(k1 & 0x3Fu);
    const float v1 = __uint_as_float(k1 & 0xFFFFFFC0u);
    const float v2 = __uint_as_float(__float_as_uint(s2) & 0xFFFFFFC0u);
    const bool ok = (1.0f - v1) <= 0.64f * (1.0f - v2);
    m1[i] = ok ? row : -1;
  }
}

// ---- mutual check + output ----
__global__ __launch_bounds__(256)
void finalize_kernel(const int* __restrict__ m0, const float* __restrict__ s0,
                     const int* __restrict__ m1, float* __restrict__ out)
{
  const int idx = blockIdx.x * 256 + threadIdx.x;
  if (idx >= B_ * N_) return;
  const int b = idx >> 12;
  const int n = idx & (N_ - 1);
  const int mm = m0[idx];
  int res = -1;
  if (mm > -1 && m1[((size_t)b << 12) + mm] == n) res = mm;
  out[idx] = (float)res;
  out[B_ * N_ + idx] = s0[idx];
}

extern "C" void kernel_launch(void* const* d_in, const int* in_sizes, int n_in,
                              void* d_out, int out_size, void* d_ws, size_t ws_size,
                              hipStream_t stream)
{
  const float* d0 = (const float*)d_in[0];
  const float* d1 = (const float*)d_in[1];
  float* out = (float*)d_out;

  uchar* At = (uchar*)((char*)d_ws + OFF_AT);
  uchar* Bt = (uchar*)((char*)d_ws + OFF_BT);
  uint2* PR = (uint2*)((char*)d_ws + OFF_PR);
  uint2* PC = (uint2*)((char*)d_ws + OFF_PC);
  int*   m0 = (int*)  ((char*)d_ws + OFF_M0);
  float* s0 = (float*)((char*)d_ws + OFF_S0);
  int*   m1 = (int*)  ((char*)d_ws + OFF_M1);

  prep_kernel<<<dim3(N_ / 128, D_ / 32, 16), 256, 0, stream>>>(d0, d1, At, Bt);
  nn_pass<<<dim3(B_ * (N_ / BMR) * CSPLIT), 256, 0, stream>>>(At, Bt, PR, PC);
  merge_kernel<<<dim3(2 * B_ * N_ / 256), 256, 0, stream>>>(PR, PC, m0, s0, m1);
  finalize_kernel<<<dim3(B_ * N_ / 256), 256, 0, stream>>>(m0, s0, m1, out);
}

// Round 9
// 77.336 us; speedup vs baseline: 2.1658x; 1.0565x over previous
//
#include <hip/hip_runtime.h>

// NearestNeighbor b=8, d=256, n=m=4096.
// Round 9: r8 + (a) full-tile B double-buffer, ONE barrier per tile;
// (b) merge+finalize fused. Frag-tiled fp8 panels, A-frags in registers.

typedef unsigned int uint;
typedef unsigned char uchar;
typedef int i32x4 __attribute__((ext_vector_type(4)));
typedef int i32x8 __attribute__((ext_vector_type(8)));
typedef float f32x4 __attribute__((ext_vector_type(4)));

constexpr int B_ = 8, D_ = 256, N_ = 4096;
constexpr int BMR = 128;                       // rows per block
constexpr int BNT = 128;                       // cols per tile iteration
constexpr int CSPLIT = 2;                      // column split
constexpr int MT_ITERS = (N_ / CSPLIT) / BNT;  // 16

// Unified frag-tiled panel layout (per batch, 1 MB):
// element (n,k): seg=n>>7, q=(n>>6)&1, r4=(n>>4)&3, i16=n&15;
//               ks=k>>7, g=(k>>5)&3, h=(k>>4)&1, kb=k&15
// off = seg*32768 + ks*16384 + ((q*4+r4)*2+h)*1024 + (g*16+i16)*16 + kb

// workspace layout (bytes)
constexpr size_t SZ_PANEL = (size_t)B_ * N_ * D_;        // 8.39 MB (fp8)
constexpr size_t OFF_AT = 0;
constexpr size_t OFF_BT = SZ_PANEL;
constexpr size_t OFF_PR = 2 * SZ_PANEL;                  // row partials: 4 slots
constexpr size_t SZ_PR  = (size_t)4 * B_ * N_ * 8;       // 1 MB
constexpr size_t OFF_PC = OFF_PR + SZ_PR;                // col partials: 64 slots

// f32 -> OCP e4m3fn (RNE, saturating).
__device__ __forceinline__ uchar f2e4m3(float f) {
  uint u = __float_as_uint(f);
  uint s = (u >> 24) & 0x80u;
  uint mag = u & 0x7FFFFFFFu;
  if (mag >= 0x43E00000u) return (uchar)(s | 0x7Eu);
  int e = (int)(mag >> 23) - 127;
  if (e >= -6) {
    uint m = (mag >> 20) & 7u;
    uint rem = mag & 0xFFFFFu;
    m += (rem > 0x80000u) || (rem == 0x80000u && (m & 1u));
    uint ef = (uint)(e + 7);
    if (m == 8u) { m = 0u; ef += 1u; }
    if (ef >= 16u) return (uchar)(s | 0x7Eu);
    return (uchar)(s | (ef << 3) | m);
  } else {
    int q = __float2int_rn(__uint_as_float(mag) * 512.0f);
    if (q >= 8) return (uchar)(s | 0x08u);
    return (uchar)(s | (uint)q);
  }
}

__device__ __forceinline__ void glds16(const void* g, void* l) {
  __builtin_amdgcn_global_load_lds(
      (const __attribute__((address_space(1))) void*)(uintptr_t)(g),
      (__attribute__((address_space(3))) void*)(uint32_t)(uintptr_t)(l),
      16, 0, 0);
}

__device__ __forceinline__ float packkey(float v, uint mask, uint tag) {
  return __uint_as_float((__float_as_uint(v) & mask) | tag);
}

__device__ __forceinline__ float med3f(float a, float b, float c) {
#if __has_builtin(__builtin_amdgcn_fmed3f)
  return __builtin_amdgcn_fmed3f(a, b, c);
#else
  return fmaxf(fminf(a, b), fminf(fmaxf(a, b), c));
#endif
}

__device__ __forceinline__ void top2p(float& s1, float& s2, float k0, float k1) {
  const float mid = med3f(s1, k0, k1);
  s1 = fmaxf(fmaxf(s1, k0), k1);
  s2 = fmaxf(s2, mid);
}

__device__ __forceinline__ void top2merge(float& s1, float& s2, float o1, float o2) {
  const float lo = fminf(s1, o1);
  s1 = fmaxf(s1, o1);
  s2 = fmaxf(lo, fmaxf(s2, o2));
}

// ---- prep: [b][256][4096] f32 -> frag-tiled fp8 panel ----
__global__ __launch_bounds__(256)
void prep_kernel(const float* __restrict__ in0, const float* __restrict__ in1,
                 uchar* __restrict__ At, uchar* __restrict__ Bt)
{
  __shared__ uchar tile[128][44];
  const int bz = blockIdx.z;
  const float* src = (bz < 8) ? in0 : in1;
  uchar* dst = (bz < 8) ? At : Bt;
  const int b = bz & 7;
  const int n0 = blockIdx.x * 128;
  const int k0b = blockIdx.y * 32;
  const int t = threadIdx.x;

  const int kq = t >> 5;            // k-quad 0..7
  const int n4 = (t & 31) * 4;
  const float* pin = src + ((size_t)b * D_ + k0b + kq * 4) * N_ + n0 + n4;
  float4 v[4];
  #pragma unroll
  for (int j = 0; j < 4; ++j) v[j] = *(const float4*)(pin + (size_t)j * N_);
  #pragma unroll
  for (int i = 0; i < 4; ++i) {
    uchar4 o = make_uchar4(f2e4m3(((const float*)&v[0])[i]),
                           f2e4m3(((const float*)&v[1])[i]),
                           f2e4m3(((const float*)&v[2])[i]),
                           f2e4m3(((const float*)&v[3])[i]));
    *(uchar4*)&tile[n4 + i][kq * 4] = o;
  }
  __syncthreads();

  const int nl = t & 127, h = t >> 7;
  const int kg = k0b + h * 16;
  const int ks = kg >> 7, g = (kg >> 5) & 3, hh = (kg >> 4) & 1;
  const int q = (nl >> 6) & 1, r4 = (nl >> 4) & 3, i16 = nl & 15;
  i32x4 val;
  #pragma unroll
  for (int j = 0; j < 4; ++j)
    val[j] = *(const int*)&tile[nl][h * 16 + j * 4];
  uchar* po = dst + (size_t)b * (N_ * D_) + (size_t)blockIdx.x * 32768 +
              ks * 16384 + ((q * 4 + r4) * 2 + hh) * 1024 + (g * 16 + i16) * 16;
  *(i32x4*)po = val;
}

// ---- fused GEMM (MX-fp8 K=128) + dual-direction top-2 ----
// Full-tile B double buffer, one barrier per tile. A-frags in registers.
__global__ __launch_bounds__(256, 2)
void nn_pass(const uchar* __restrict__ A, const uchar* __restrict__ Bp,
             uint2* __restrict__ partR, uint2* __restrict__ partC)
{
  __shared__ uchar Bs[2][32768];   // 2 x full 128-col tile (both K-halves)

  const int t = threadIdx.x;
  const int bid = blockIdx.x;
  const int b = bid & 7;                   // XCD-pinned batch
  const int rb = (bid >> 3) & 31;
  const int cs = bid >> 8;                 // 0..1
  const size_t bOff = (size_t)b * (N_ * D_);
  const int r0 = rb * BMR;

  const int l = t & 63, wid = t >> 6, wm = wid >> 1, wn = wid & 1;
  const int l15 = l & 15, g = l >> 4;
  const int lds0 = t * 16;

  const uchar* Aseg = A + bOff + (size_t)rb * 32768;
  const uchar* Bb = Bp + bOff + (size_t)cs * 524288;   // cs half: 16 tiles x 32KB

  // prologue: stage full tile 0 into buf0; load A-frags from global (coalesced)
  #pragma unroll
  for (int i = 0; i < 8; ++i)
    glds16(Bb + i * 4096 + lds0, (char*)Bs[0] + i * 4096 + lds0);

  i32x8 af[2][4];
  #pragma unroll
  for (int ks = 0; ks < 2; ++ks)
    #pragma unroll
    for (int mi = 0; mi < 4; ++mi) {
      const uchar* p = Aseg + ks * 16384 + ((wm * 4 + mi) * 2) * 1024 + l * 16;
      const i32x4 lo = *(const i32x4*)p;
      const i32x4 hi = *(const i32x4*)(p + 1024);
      af[ks][mi] = __builtin_shufflevector(lo, hi, 0, 1, 2, 3, 4, 5, 6, 7);
    }
  __syncthreads();

  const float NEG = __uint_as_float(0xFF800000u);  // -inf
  float rs1[4][4], rs2[4][4];
  #pragma unroll
  for (int mi = 0; mi < 4; ++mi)
    #pragma unroll
    for (int rg = 0; rg < 4; ++rg) { rs1[mi][rg] = NEG; rs2[mi][rg] = NEG; }

  float cp1[4], cp2[4];

  #pragma unroll 1
  for (int mt = 0; mt < MT_ITERS; ++mt) {
    const char* cB = (const char*)Bs[mt & 1] + l * 16;   // lane-linear base

    // stage next full tile into the other buffer (drains at end-of-tile barrier)
    if (mt + 1 < MT_ITERS) {
      const uchar* Bnx = Bb + (size_t)(mt + 1) * 32768;
      #pragma unroll
      for (int i = 0; i < 8; ++i)
        glds16(Bnx + i * 4096 + lds0, (char*)Bs[(mt + 1) & 1] + i * 4096 + lds0);
    }

    // deferred partC store for tile mt-1
    if (mt > 0 && g == 0) {
      const int cbp = (mt - 1) * BNT + wn * 64;
      #pragma unroll
      for (int ni = 0; ni < 4; ++ni)
        partC[((size_t)(rb * 2 + wm) * B_ + b) * N_ + cs * 2048 + cbp + ni * 16 + l15] =
            make_uint2(__float_as_uint(cp1[ni]), __float_as_uint(cp2[ni]));
    }

    f32x4 acc[4][4];
    #pragma unroll
    for (int mi = 0; mi < 4; ++mi)
      #pragma unroll
      for (int ni = 0; ni < 4; ++ni) acc[mi][ni] = (f32x4){0.f, 0.f, 0.f, 0.f};

    // ---- half ks=0 ----
    #pragma unroll
    for (int ni = 0; ni < 4; ++ni) {
      const int imm = ((wn * 4 + ni) * 2) * 1024;
      const i32x4 lo = *(const i32x4*)(cB + imm);
      const i32x4 hi = *(const i32x4*)(cB + imm + 1024);
      const i32x8 bf = __builtin_shufflevector(lo, hi, 0, 1, 2, 3, 4, 5, 6, 7);
      __builtin_amdgcn_s_setprio(1);
      #pragma unroll
      for (int mi = 0; mi < 4; ++mi)
        acc[mi][ni] = __builtin_amdgcn_mfma_scale_f32_16x16x128_f8f6f4(
            af[0][mi], bf, acc[mi][ni], 0, 0, 0, 127, 0, 127);
      __builtin_amdgcn_s_setprio(0);
    }
    // ---- half ks=1 ----
    #pragma unroll
    for (int ni = 0; ni < 4; ++ni) {
      const int imm = 16384 + ((wn * 4 + ni) * 2) * 1024;
      const i32x4 lo = *(const i32x4*)(cB + imm);
      const i32x4 hi = *(const i32x4*)(cB + imm + 1024);
      const i32x8 bf = __builtin_shufflevector(lo, hi, 0, 1, 2, 3, 4, 5, 6, 7);
      __builtin_amdgcn_s_setprio(1);
      #pragma unroll
      for (int mi = 0; mi < 4; ++mi)
        acc[mi][ni] = __builtin_amdgcn_mfma_scale_f32_16x16x128_f8f6f4(
            af[1][mi], bf, acc[mi][ni], 0, 0, 0, 127, 0, 127);
      __builtin_amdgcn_s_setprio(0);
    }

    // ---- fold: row direction (persistent) ----
    const int colb = mt * BNT + wn * 64;
    const uint tg0 = (uint)(2047 - (colb + l15));
    #pragma unroll
    for (int mi = 0; mi < 4; ++mi)
      #pragma unroll
      for (int rg = 0; rg < 4; ++rg) {
        const float k0 = packkey(acc[mi][0][rg], 0xFFFFF800u, tg0);
        const float k1 = packkey(acc[mi][1][rg], 0xFFFFF800u, tg0 - 16);
        const float k2 = packkey(acc[mi][2][rg], 0xFFFFF800u, tg0 - 32);
        const float k3 = packkey(acc[mi][3][rg], 0xFFFFF800u, tg0 - 48);
        top2p(rs1[mi][rg], rs2[mi][rg], k0, k1);
        top2p(rs1[mi][rg], rs2[mi][rg], k2, k3);
      }
    // ---- fold: col direction ----
    const uint tgb = (uint)(63 - g * 4);
    #pragma unroll
    for (int ni = 0; ni < 4; ++ni) {
      float c1 = NEG, c2 = NEG;
      #pragma unroll
      for (int mi = 0; mi < 4; ++mi) {
        const float k0 = packkey(acc[mi][ni][0], 0xFFFFFFC0u, tgb - (uint)(mi * 16));
        const float k1 = packkey(acc[mi][ni][1], 0xFFFFFFC0u, tgb - (uint)(mi * 16 + 1));
        const float k2 = packkey(acc[mi][ni][2], 0xFFFFFFC0u, tgb - (uint)(mi * 16 + 2));
        const float k3 = packkey(acc[mi][ni][3], 0xFFFFFFC0u, tgb - (uint)(mi * 16 + 3));
        top2p(c1, c2, k0, k1);
        top2p(c1, c2, k2, k3);
      }
      #pragma unroll
      for (int off = 16; off <= 32; off <<= 1) {
        const float o1 = __shfl_xor(c1, off);
        const float o2 = __shfl_xor(c2, off);
        top2merge(c1, c2, o1, o2);
      }
      cp1[ni] = c1; cp2[ni] = c2;
    }
    __syncthreads();   // ONE barrier per tile: stage drained, buf swap safe
  }

  // final col-partial store
  if (g == 0) {
    const int cbp = (MT_ITERS - 1) * BNT + wn * 64;
    #pragma unroll
    for (int ni = 0; ni < 4; ++ni)
      partC[((size_t)(rb * 2 + wm) * B_ + b) * N_ + cs * 2048 + cbp + ni * 16 + l15] =
          make_uint2(__float_as_uint(cp1[ni]), __float_as_uint(cp2[ni]));
  }

  // row merge across 16 column-lanes, write per-(cs,wn) partials
  #pragma unroll
  for (int off = 1; off < 16; off <<= 1) {
    #pragma unroll
    for (int mi = 0; mi < 4; ++mi)
      #pragma unroll
      for (int rg = 0; rg < 4; ++rg) {
        const float o1 = __shfl_xor(rs1[mi][rg], off);
        const float o2 = __shfl_xor(rs2[mi][rg], off);
        top2merge(rs1[mi][rg], rs2[mi][rg], o1, o2);
      }
  }
  if (l15 == 0) {
    #pragma unroll
    for (int mi = 0; mi < 4; ++mi)
      #pragma unroll
      for (int rg = 0; rg < 4; ++rg)
        partR[((size_t)(cs * 2 + wn) * B_ + b) * N_ + r0 + wm * 64 + mi * 16 + g * 4 + rg] =
            make_uint2(__float_as_uint(rs1[mi][rg]), __float_as_uint(rs2[mi][rg]));
  }
}

// ---- fused: fold partials, ratio test, mutual check, output ----
__global__ __launch_bounds__(256)
void finalize_kernel(const uint2* __restrict__ pR, const uint2* __restrict__ pC,
                     float* __restrict__ out)
{
  const int i = blockIdx.x * 256 + threadIdx.x;
  if (i >= B_ * N_) return;
  const int b = i >> 12;
  const int n = i & (N_ - 1);
  const float NEG = __uint_as_float(0xFF800000u);

  // row direction: matches0 candidate + score
  float s1 = NEG, s2 = NEG; int bs = 0;
  #pragma unroll
  for (int sl = 0; sl < 4; ++sl) {
    const uint2 v = pR[(size_t)sl * B_ * N_ + i];
    const float o1 = __uint_as_float(v.x), o2 = __uint_as_float(v.y);
    bs = (o1 > s1) ? sl : bs;
    top2merge(s1, s2, o1, o2);
  }
  const uint k1 = __float_as_uint(s1);
  const int col = (bs >> 1) * 2048 + 2047 - (int)(k1 & 0x7FFu);
  const float v1 = __uint_as_float(k1 & 0xFFFFF800u);
  const float v2 = __uint_as_float(__float_as_uint(s2) & 0xFFFFF800u);
  const bool ok = (1.0f - v1) <= 0.64f * (1.0f - v2);   // Lowe 0.8^2

  out[B_ * N_ + i] = ok ? (v1 + 1.0f) * 0.5f : 0.0f;    // scores0 (no mutual mask)

  int res = -1;
  if (ok) {
    // col direction at column `col`: matches1[b][col], only when needed (rare)
    float c1 = NEG, c2 = NEG; int cbs = 0;
    const uint2* pcb = pC + (size_t)b * N_ + col;
    #pragma unroll 8
    for (int sl = 0; sl < 64; ++sl) {
      const uint2 v = pcb[(size_t)sl * B_ * N_];
      const float o1 = __uint_as_float(v.x), o2 = __uint_as_float(v.y);
      cbs = (o1 > c1) ? sl : cbs;
      top2merge(c1, c2, o1, o2);
    }
    const uint ck1 = __float_as_uint(c1);
    const int row = cbs * 64 + 63 - (int)(ck1 & 0x3Fu);
    const float cv1 = __uint_as_float(ck1 & 0xFFFFFFC0u);
    const float cv2 = __uint_as_float(__float_as_uint(c2) & 0xFFFFFFC0u);
    const bool cok = (1.0f - cv1) <= 0.64f * (1.0f - cv2);
    if (cok && row == n) res = col;
  }
  out[i] = (float)res;
}

extern "C" void kernel_launch(void* const* d_in, const int* in_sizes, int n_in,
                              void* d_out, int out_size, void* d_ws, size_t ws_size,
                              hipStream_t stream)
{
  const float* d0 = (const float*)d_in[0];
  const float* d1 = (const float*)d_in[1];
  float* out = (float*)d_out;

  uchar* At = (uchar*)((char*)d_ws + OFF_AT);
  uchar* Bt = (uchar*)((char*)d_ws + OFF_BT);
  uint2* PR = (uint2*)((char*)d_ws + OFF_PR);
  uint2* PC = (uint2*)((char*)d_ws + OFF_PC);

  prep_kernel<<<dim3(N_ / 128, D_ / 32, 16), 256, 0, stream>>>(d0, d1, At, Bt);
  nn_pass<<<dim3(B_ * (N_ / BMR) * CSPLIT), 256, 0, stream>>>(At, Bt, PR, PC);
  finalize_kernel<<<dim3(B_ * N_ / 256), 256, 0, stream>>>(PR, PC, out);
}